// Round 10
// baseline (125.478 us; speedup 1.0000x reference)
//
#include <hip/hip_runtime.h>

typedef __bf16 bf16;
typedef __bf16 bf16x8 __attribute__((ext_vector_type(8)));
typedef float f32x4 __attribute__((ext_vector_type(4)));

static_assert(sizeof(bf16x8) == 16, "bf16x8 must be 16B");

#define MFMA16x16x32(a, b, c) __builtin_amdgcn_mfma_f32_16x16x32_bf16((a), (b), (c), 0, 0, 0)

// problem constants
#define NB 2
#define NL 1024
#define ND 1024
#define NH 16
#define NHD 64
#define NP 2047
#define NBH (NB * NH)  // 32

// wave-synchronous LDS fence (wave-private LDS slices): no vmcnt drain
__device__ __forceinline__ void wave_sync_lds() {
  __builtin_amdgcn_sched_barrier(0);
  asm volatile("s_waitcnt lgkmcnt(0)" ::: "memory");
  __builtin_amdgcn_sched_barrier(0);
}

// async global->LDS, 16B per lane, wave-linear dest
__device__ __forceinline__ void gload16(const bf16* g, bf16* lds) {
  __builtin_amdgcn_global_load_lds((const __attribute__((address_space(1))) void*)g,
                                   (__attribute__((address_space(3))) void*)lds, 16, 0, 0);
}

// ---------------- kernel 0: split f32 -> hi/lo bf16 (used for X) ----------------
__global__ __launch_bounds__(256) void split_er_k(const float* __restrict__ er,
                                                  bf16* __restrict__ hi,
                                                  bf16* __restrict__ lo, int n) {
  int i = blockIdx.x * 256 + threadIdx.x;
  if (i < n) {
    float v = er[i];
    bf16 h = (bf16)v;
    hi[i] = h;
    lo[i] = (bf16)(v - (float)h);
  }
}

// ---------------- kernel 0c: pack Er into A-frag-major tiles (hi/lo) ----------------
__global__ __launch_bounds__(256) void er_pack_k(const float* __restrict__ er,
                                                 bf16* __restrict__ eph,
                                                 bf16* __restrict__ epl) {
  const int i = blockIdx.x * 256 + threadIdx.x;  // 2^21 total
  const int e = i & 7;
  const int lane = (i >> 3) & 63;
  const int half = (i >> 9) & 1;
  const int ob = (i >> 10) & 127;
  const int h = i >> 17;
  const int g = lane >> 4, cl = lane & 15;
  const int o = ob * 16 - 1024 + cl;
  const int p = (o <= 0) ? -o : (NP - o);
  const int d = half * 32 + g * 8 + e;
  float v = er[(size_t)(h * NP + p) * NHD + d];
  bf16 hv = (bf16)v;
  eph[i] = hv;
  epl[i] = (bf16)(v - (float)hv);
}

// ---------------- kernel 0b: transpose + split W [K][N] f32 -> WT [N][K] bf16 ----------------
__global__ __launch_bounds__(256) void trans_split_k(const float* __restrict__ W, int N, int K,
                                                     int n_lo, bf16* __restrict__ WT_h,
                                                     bf16* __restrict__ WT_l) {
  __shared__ float tile[64][68];
  const int n0 = blockIdx.x * 64, k0 = blockIdx.y * 64;
  const int t = threadIdx.x;
  const int rc = t & 15;
  const int rr0 = t >> 4;
#pragma unroll
  for (int i = 0; i < 4; ++i) {
    const int row = rr0 + i * 16;
    float4 v = *(const float4*)(W + (size_t)(k0 + row) * N + n0 + rc * 4);
    *(float4*)&tile[row][rc * 4] = v;
  }
  __syncthreads();
  const int n = t >> 2, kc = (t & 3) * 16;
  bf16x8 h0, h1, l0, l1;
#pragma unroll
  for (int e = 0; e < 8; ++e) {
    float v = tile[kc + e][n];
    bf16 hh = (bf16)v;
    h0[e] = hh;
    l0[e] = (bf16)(v - (float)hh);
  }
#pragma unroll
  for (int e = 0; e < 8; ++e) {
    float v = tile[kc + 8 + e][n];
    bf16 hh = (bf16)v;
    h1[e] = hh;
    l1[e] = (bf16)(v - (float)hh);
  }
  bf16* dst = WT_h + (size_t)(n0 + n) * K + k0 + kc;
  *(bf16x8*)dst = h0;
  *(bf16x8*)(dst + 8) = h1;
  if (WT_l != nullptr && (n0 + n) < n_lo) {
    bf16* dstl = WT_l + (size_t)(n0 + n) * K + k0 + kc;
    *(bf16x8*)dstl = l0;
    *(bf16x8*)(dstl + 8) = l1;
  }
}

// ---------------- kernel 1: QKV projection GEMM ----------------
// 128x128 tile, BK=32, 4 waves each owning a 64x64 quadrant (m97-structure).
// gload16 staging with T2 source swizzle; 3-term hi/lo for Q section.
__global__ __launch_bounds__(256) void qkv_gemm_k(const bf16* __restrict__ Xh,
                                                  const bf16* __restrict__ Xl,
                                                  const bf16* __restrict__ WTh,
                                                  const bf16* __restrict__ WTl,
                                                  const float* __restrict__ bias,
                                                  bf16* __restrict__ qh, bf16* __restrict__ ql,
                                                  bf16* __restrict__ kp, bf16* __restrict__ vp) {
  __shared__ bf16 sAh[128 * 32], sAl[128 * 32], sBh[128 * 32], sBl[128 * 32];
  const int t = threadIdx.x;
  const int lane = t & 63;
  const int w = t >> 6;
  const int cl = lane & 15;
  const int g = lane >> 4;
  const int m0 = blockIdx.x * 128;
  const int n0 = blockIdx.y * 128;
  const bool isQ = (n0 < ND);
  const int wm = w & 1, wn = w >> 1;  // wave quadrant (64x64)

  // staging: per wave 2 instr per 128-row buffer (16 rows each wave-instr)
  const int srow = w * 16 + (lane >> 2);    // A rows [0,64) first instr, +64 second
  const int brow = w * 32 + (lane >> 2);    // B rows: brow and brow+16
  const int scol = ((lane & 3) ^ ((lane >> 3) & 3)) * 8;  // T2 source swizzle
  const int rsw = (g ^ ((cl >> 1) & 3)) * 8;              // swizzled read col
  bf16* ldsA0 = &sAh[w * 512];
  bf16* ldsA1 = &sAh[2048 + w * 512];
  bf16* ldsAl0 = &sAl[w * 512];
  bf16* ldsAl1 = &sAl[2048 + w * 512];
  bf16* ldsB0 = &sBh[w * 1024];
  bf16* ldsB1 = &sBh[w * 1024 + 512];
  bf16* ldsBl0 = &sBl[w * 1024];
  bf16* ldsBl1 = &sBl[w * 1024 + 512];

  f32x4 acc[4][4] = {};

  for (int k0 = 0; k0 < ND; k0 += 32) {
    gload16(Xh + (size_t)(m0 + srow) * ND + k0 + scol, ldsA0);
    gload16(Xh + (size_t)(m0 + 64 + srow) * ND + k0 + scol, ldsA1);
    const bf16* gb = WTh + (size_t)(n0 + brow) * ND + k0 + scol;
    gload16(gb, ldsB0);
    gload16(gb + (size_t)16 * ND, ldsB1);
    if (isQ) {
      gload16(Xl + (size_t)(m0 + srow) * ND + k0 + scol, ldsAl0);
      gload16(Xl + (size_t)(m0 + 64 + srow) * ND + k0 + scol, ldsAl1);
      const bf16* gbl = WTl + (size_t)(n0 + brow) * ND + k0 + scol;
      gload16(gbl, ldsBl0);
      gload16(gbl + (size_t)16 * ND, ldsBl1);
    }
    __syncthreads();

    bf16x8 ah[4], bh[4];
#pragma unroll
    for (int fm = 0; fm < 4; ++fm)
      ah[fm] = *(const bf16x8*)&sAh[(wm * 64 + fm * 16 + cl) * 32 + rsw];
#pragma unroll
    for (int fn = 0; fn < 4; ++fn)
      bh[fn] = *(const bf16x8*)&sBh[(wn * 64 + fn * 16 + cl) * 32 + rsw];
    if (isQ) {
      bf16x8 al[4], bl[4];
#pragma unroll
      for (int fm = 0; fm < 4; ++fm)
        al[fm] = *(const bf16x8*)&sAl[(wm * 64 + fm * 16 + cl) * 32 + rsw];
#pragma unroll
      for (int fn = 0; fn < 4; ++fn)
        bl[fn] = *(const bf16x8*)&sBl[(wn * 64 + fn * 16 + cl) * 32 + rsw];
#pragma unroll
      for (int fm = 0; fm < 4; ++fm)
#pragma unroll
        for (int fn = 0; fn < 4; ++fn) {
          acc[fm][fn] = MFMA16x16x32(ah[fm], bh[fn], acc[fm][fn]);
          acc[fm][fn] = MFMA16x16x32(ah[fm], bl[fn], acc[fm][fn]);
          acc[fm][fn] = MFMA16x16x32(al[fm], bh[fn], acc[fm][fn]);
        }
    } else {
#pragma unroll
      for (int fm = 0; fm < 4; ++fm)
#pragma unroll
        for (int fn = 0; fn < 4; ++fn)
          acc[fm][fn] = MFMA16x16x32(ah[fm], bh[fn], acc[fm][fn]);
    }
    __syncthreads();
  }

  // epilogue: bias + scatter into attention layouts (K/V frag-packed)
#pragma unroll
  for (int fm = 0; fm < 4; ++fm) {
#pragma unroll
    for (int fn = 0; fn < 4; ++fn) {
#pragma unroll
      for (int reg = 0; reg < 4; ++reg) {
        const int gm = m0 + wm * 64 + fm * 16 + g * 4 + reg;  // token row
        const int gn = n0 + wn * 64 + fn * 16 + cl;           // qkv col
        float val = acc[fm][fn][reg] + bias[gn];
        const int bb = gm >> 10, lpos = gm & 1023;
        const int sec = gn >> 10, hc = gn & 1023;
        const int hh = hc >> 6, dd = hc & 63;
        const int bh = bb * NH + hh;
        if (sec == 0) {
          bf16 hi = (bf16)val;
          qh[(size_t)(bh * NL + lpos) * NHD + dd] = hi;
          ql[(size_t)(bh * NL + lpos) * NHD + dd] = (bf16)(val - (float)hi);
        } else if (sec == 1) {
          const size_t idx = ((size_t)((bh * 64 + (lpos >> 4)) * 2 + (dd >> 5))) * 512 +
                             ((((dd >> 3) & 3) << 4) + (lpos & 15)) * 8 + (dd & 7);
          kp[idx] = (bf16)val;
        } else {
          const size_t idx = ((size_t)(((bh * 16 + (lpos >> 6)) * 4 + (dd >> 4)) * 2 +
                                       ((lpos >> 5) & 1))) * 512 +
                             ((((lpos >> 3) & 3) << 4) + (dd & 15)) * 8 + (lpos & 7);
          vp[idx] = (bf16)val;
        }
      }
    }
  }
}

// ---------------- kernel 2: attention (unchanged from R9) ----------------
__global__ __launch_bounds__(256) void attn_k(const bf16* __restrict__ qh, const bf16* __restrict__ ql,
                                              const bf16* __restrict__ kp, const bf16* __restrict__ vp,
                                              const bf16* __restrict__ eph, const bf16* __restrict__ epl,
                                              bf16* __restrict__ ao) {
  __shared__ float s_lds[4][16][67];
  __shared__ bf16 p_lds[4][16][72];
  __shared__ float mb[4][16], lbuf[4][16], linv[16];

  const int t = threadIdx.x;
  const int w = t >> 6;
  const int lane = t & 63;
  const int cl = lane & 15;
  const int g = lane >> 4;

  const int n = blockIdx.x;
  const int xcd = n & 7, idx = n >> 3;
  const int bh = (xcd << 2) | (idx >> 6);
  const int itile = 63 - (idx & 63);
  const int i0 = itile * 16;
  const int h = bh & (NH - 1);
  const int nchunks = (itile >> 2) + 1;

  const bf16* qhb = qh + (size_t)(bh * NL + i0 + cl) * NHD + g * 8;
  const bf16* qlb = ql + (size_t)(bh * NL + i0 + cl) * NHD + g * 8;
  const bf16x8 q_h0 = *(const bf16x8*)qhb;
  const bf16x8 q_h1 = *(const bf16x8*)(qhb + 32);
  const bf16x8 q_l0 = *(const bf16x8*)qlb;
  const bf16x8 q_l1 = *(const bf16x8*)(qlb + 32);

  f32x4 acc_o[4] = {};
  float m_s = -3e38f, l_s = 0.0f;

  for (int jc = w; jc < nchunks; jc += 4) {
    const int j0 = jc * 64;
    const int delta = i0 - j0;

    const bf16* vbase = vp + ((size_t)(bh * 16 + (j0 >> 6)) * 8) * 512 + lane * 8;
    bf16x8 vf[4][2];
#pragma unroll
    for (int t4 = 0; t4 < 4; ++t4) {
      vf[t4][0] = *(const bf16x8*)(vbase + (t4 * 2 + 0) * 512);
      vf[t4][1] = *(const bf16x8*)(vbase + (t4 * 2 + 1) * 512);
    }

    const bf16* kbase = kp + ((size_t)(bh * 64 + (j0 >> 4)) * 2) * 512 + lane * 8;
    f32x4 acc_s[4];
    __builtin_amdgcn_s_setprio(1);
#pragma unroll
    for (int jn = 0; jn < 4; ++jn) {
      bf16x8 kf0 = *(const bf16x8*)(kbase + (jn * 2 + 0) * 512);
      bf16x8 kf1 = *(const bf16x8*)(kbase + (jn * 2 + 1) * 512);
      f32x4 a = {};
      a = MFMA16x16x32(q_h0, kf0, a);
      a = MFMA16x16x32(q_h1, kf1, a);
      acc_s[jn] = a;
    }

    const int ob0 = (delta >> 4) + 60;
    const bf16* ebh_base = eph + ((size_t)(h * 128 + ob0) * 2) * 512 + lane * 8;
    const bf16* ebl_base = epl + ((size_t)(h * 128 + ob0) * 2) * 512 + lane * 8;
    f32x4 acc_e[5];
#pragma unroll
    for (int tt = 0; tt < 5; ++tt) {
      bf16x8 eh0 = *(const bf16x8*)(ebh_base + (tt * 2 + 0) * 512);
      bf16x8 eh1 = *(const bf16x8*)(ebh_base + (tt * 2 + 1) * 512);
      bf16x8 el0 = *(const bf16x8*)(ebl_base + (tt * 2 + 0) * 512);
      bf16x8 el1 = *(const bf16x8*)(ebl_base + (tt * 2 + 1) * 512);
      f32x4 c1 = {}, c2 = {};
      c1 = MFMA16x16x32(q_h0, eh0, c1);
      c1 = MFMA16x16x32(q_h1, eh1, c1);
      c2 = MFMA16x16x32(q_h0, el0, c2);
      c2 = MFMA16x16x32(q_h1, el1, c2);
      c2 = MFMA16x16x32(q_l0, eh0, c2);
      c2 = MFMA16x16x32(q_l1, eh1, c2);
      acc_e[tt] = c1 + c2;
    }
    __builtin_amdgcn_s_setprio(0);

#pragma unroll
    for (int reg = 0; reg < 4; ++reg) {
      const int r = g * 4 + reg;
      const int src = (g << 4) | ((r - cl) & 15);
      const bool ge = (r >= cl);
#pragma unroll
      for (int jn = 0; jn < 4; ++jn) {
        float e_hi = __shfl(acc_e[4 - jn][reg], src);
        float e_lo = __shfl(acc_e[3 - jn][reg], src);
        s_lds[w][r][jn * 16 + cl] = fmaf(acc_s[jn][reg], 0.125f, ge ? e_hi : e_lo);
      }
    }
    wave_sync_lds();

    float sv[16];
    float tmax = -3e38f;
#pragma unroll
    for (int cc = 0; cc < 16; ++cc) {
      const int c = g * 16 + cc;
      float v = s_lds[w][cl][c];
      if (c > delta + cl) v = -3e38f;
      sv[cc] = v;
      tmax = fmaxf(tmax, v);
    }
    tmax = fmaxf(tmax, __shfl_xor(tmax, 16));
    tmax = fmaxf(tmax, __shfl_xor(tmax, 32));
    const float m_new = fmaxf(m_s, tmax);
    const float fsc = __builtin_amdgcn_exp2f((m_s - m_new) * 1.44269504f);
    float psum = 0.0f;
    bf16x8 plo, phi;
#pragma unroll
    for (int cc = 0; cc < 16; ++cc) {
      float pv = __builtin_amdgcn_exp2f((sv[cc] - m_new) * 1.44269504f);
      psum += pv;
      if (cc < 8) plo[cc & 7] = (bf16)pv;
      else        phi[cc & 7] = (bf16)pv;
    }
    psum += __shfl_xor(psum, 16);
    psum += __shfl_xor(psum, 32);
    l_s = l_s * fsc + psum;
    m_s = m_new;

    *(bf16x8*)&p_lds[w][cl][g * 16] = plo;
    *(bf16x8*)&p_lds[w][cl][g * 16 + 8] = phi;
    wave_sync_lds();
    bf16x8 pf0 = *(const bf16x8*)&p_lds[w][cl][g * 8];
    bf16x8 pf1 = *(const bf16x8*)&p_lds[w][cl][32 + g * 8];

    float fr[4];
#pragma unroll
    for (int reg = 0; reg < 4; ++reg) fr[reg] = __shfl(fsc, g * 4 + reg);
#pragma unroll
    for (int t4 = 0; t4 < 4; ++t4) {
#pragma unroll
      for (int reg = 0; reg < 4; ++reg) acc_o[t4][reg] *= fr[reg];
    }
    __builtin_amdgcn_s_setprio(1);
#pragma unroll
    for (int t4 = 0; t4 < 4; ++t4) {
      acc_o[t4] = MFMA16x16x32(pf0, vf[t4][0], acc_o[t4]);
      acc_o[t4] = MFMA16x16x32(pf1, vf[t4][1], acc_o[t4]);
    }
    __builtin_amdgcn_s_setprio(0);
  }

  if (lane < 16) {
    mb[w][lane] = m_s;
    lbuf[w][lane] = l_s;
  }
  __syncthreads();
  const float M = fmaxf(fmaxf(mb[0][cl], mb[1][cl]), fmaxf(mb[2][cl], mb[3][cl]));
  const float sc = __builtin_amdgcn_exp2f((m_s - M) * 1.44269504f);
  float Lt = 0.0f;
#pragma unroll
  for (int ww = 0; ww < 4; ++ww)
    Lt += lbuf[ww][cl] * __builtin_amdgcn_exp2f((mb[ww][cl] - M) * 1.44269504f);
  if (w == 0 && lane < 16) linv[lane] = 1.0f / Lt;
  float fr2[4];
#pragma unroll
  for (int reg = 0; reg < 4; ++reg) fr2[reg] = __shfl(sc, g * 4 + reg);
#pragma unroll
  for (int t4 = 0; t4 < 4; ++t4) {
#pragma unroll
    for (int reg = 0; reg < 4; ++reg)
      s_lds[w][g * 4 + reg][t4 * 16 + cl] = acc_o[t4][reg] * fr2[reg];
  }
  __syncthreads();
  const int bb = bh >> 4;
#pragma unroll
  for (int rep = 0; rep < 4; ++rep) {
    const int o_ = t + rep * 256;
    const int r = o_ >> 6, c = o_ & 63;
    float s = s_lds[0][r][c] + s_lds[1][r][c] + s_lds[2][r][c] + s_lds[3][r][c];
    ao[(size_t)(bb * NL + i0 + r) * ND + h * NHD + c] = (bf16)(s * linv[r]);
  }
}

// ---------------- kernel 3: output projection (64x128 tile, gload_lds, T2 swizzle) ----------------
__global__ __launch_bounds__(256) void out_gemm_k(const bf16* __restrict__ A,
                                                  const bf16* __restrict__ WT,
                                                  const float* __restrict__ bias,
                                                  float* __restrict__ out) {
  __shared__ bf16 sA[64 * 32], sB[128 * 32];
  const int t = threadIdx.x;
  const int lane = t & 63, w = t >> 6;
  const int cl = lane & 15, g = lane >> 4;
  const int m0 = blockIdx.x * 64;
  const int n0 = blockIdx.y * 128;

  const int arow = w * 16 + (lane >> 2);
  const int brow0 = w * 32 + (lane >> 2);
  const int scol = ((lane & 3) ^ ((lane >> 3) & 3)) * 8;
  const int rsw = (g ^ ((cl >> 1) & 3)) * 8;
  bf16* ldsA = &sA[w * 512];
  bf16* ldsB0 = &sB[w * 1024];
  bf16* ldsB1 = &sB[w * 1024 + 512];

  f32x4 acc[4][2] = {};

  for (int k0 = 0; k0 < ND; k0 += 32) {
    gload16(A + (size_t)(m0 + arow) * ND + k0 + scol, ldsA);
    const bf16* gb0 = WT + (size_t)(n0 + brow0) * ND + k0 + scol;
    gload16(gb0, ldsB0);
    gload16(gb0 + (size_t)16 * ND, ldsB1);
    __syncthreads();
    bf16x8 ah[4], bh[2];
#pragma unroll
    for (int fm = 0; fm < 4; ++fm) ah[fm] = *(const bf16x8*)&sA[(fm * 16 + cl) * 32 + rsw];
#pragma unroll
    for (int fn = 0; fn < 2; ++fn) bh[fn] = *(const bf16x8*)&sB[(w * 32 + fn * 16 + cl) * 32 + rsw];
#pragma unroll
    for (int fm = 0; fm < 4; ++fm)
#pragma unroll
      for (int fn = 0; fn < 2; ++fn)
        acc[fm][fn] = MFMA16x16x32(ah[fm], bh[fn], acc[fm][fn]);
    __syncthreads();
  }
#pragma unroll
  for (int fm = 0; fm < 4; ++fm) {
#pragma unroll
    for (int fn = 0; fn < 2; ++fn) {
#pragma unroll
      for (int reg = 0; reg < 4; ++reg) {
        const int gm = m0 + fm * 16 + g * 4 + reg;
        const int gn = n0 + w * 32 + fn * 16 + cl;
        out[(size_t)gm * ND + gn] = acc[fm][fn][reg] + bias[gn];
      }
    }
  }
}

extern "C" void kernel_launch(void* const* d_in, const int* in_sizes, int n_in,
                              void* d_out, int out_size, void* d_ws, size_t ws_size,
                              hipStream_t stream) {
  (void)in_sizes; (void)n_in; (void)out_size; (void)ws_size;
  const float* x = (const float*)d_in[0];
  // d_in[1] = causal mask — structural (triu k=1), computed inline
  const float* Wqkv = (const float*)d_in[2];
  const float* bqkv = (const float*)d_in[3];
  const float* Wo = (const float*)d_in[4];
  const float* bo = (const float*)d_in[5];
  const float* Er = (const float*)d_in[6];

  char* ws = (char*)d_ws;
  size_t off = 0;
  auto take = [&](size_t bytes) {
    char* p = ws + off;
    off += (bytes + 255) & ~(size_t)255;
    return p;
  };
  const size_t qkN = (size_t)NBH * NL * NHD;   // 2,097,152
  const size_t xN = (size_t)NB * NL * ND;      // 2,097,152
  const size_t erpN = (size_t)NH * 128 * 2 * 512;  // 2,097,152
  bf16* eph = (bf16*)take(erpN * 2);
  bf16* epl = (bf16*)take(erpN * 2);
  bf16* qhw = (bf16*)take(qkN * 2);
  bf16* qlw = (bf16*)take(qkN * 2);
  bf16* kpw = (bf16*)take(qkN * 2);    // K frag-packed
  bf16* vpw = (bf16*)take(qkN * 2);    // V frag-packed
  bf16* wqkvth = (bf16*)take((size_t)3 * ND * ND * 2);  // [3072][1024]
  bf16* wqkvtl = (bf16*)take((size_t)ND * ND * 2);      // [1024][1024] (Q section only)
  bf16* woth   = (bf16*)take((size_t)ND * ND * 2);      // [1024][1024]
  bf16* xsh    = (bf16*)take(xN * 2);                   // X hi
  bf16* xsl    = (bf16*)take(xN * 2);                   // X lo
  bf16* aow = wqkvth;  // alias: wqkvth dead after qkv_gemm, aow born in attn

  er_pack_k<<<(int)(erpN / 256), 256, 0, stream>>>(Er, eph, epl);
  split_er_k<<<(int)((xN + 255) / 256), 256, 0, stream>>>(x, xsh, xsl, (int)xN);
  trans_split_k<<<dim3(48, 16), 256, 0, stream>>>(Wqkv, 3 * ND, ND, ND, wqkvth, wqkvtl);
  trans_split_k<<<dim3(16, 16), 256, 0, stream>>>(Wo, ND, ND, 0, woth, nullptr);
  qkv_gemm_k<<<dim3(16, 24), 256, 0, stream>>>(xsh, xsl, wqkvth, wqkvtl, bqkv,
                                               qhw, qlw, kpw, vpw);
  attn_k<<<2048, 256, 0, stream>>>(qhw, qlw, kpw, vpw, eph, epl, aow);
  out_gemm_k<<<dim3(32, 8), 256, 0, stream>>>(aow, woth, bo, (float*)d_out);
}

// Round 11
// 117.295 us; speedup vs baseline: 1.0698x; 1.0698x over previous
//
#include <hip/hip_runtime.h>

typedef __bf16 bf16;
typedef __bf16 bf16x8 __attribute__((ext_vector_type(8)));
typedef _Float16 f16;
typedef _Float16 f16x8 __attribute__((ext_vector_type(8)));
typedef float f32x4 __attribute__((ext_vector_type(4)));

static_assert(sizeof(bf16x8) == 16, "bf16x8 must be 16B");
static_assert(sizeof(f16x8) == 16, "f16x8 must be 16B");

#define MFMA16x16x32(a, b, c) __builtin_amdgcn_mfma_f32_16x16x32_bf16((a), (b), (c), 0, 0, 0)
#define MFMA16x16x32F(a, b, c) __builtin_amdgcn_mfma_f32_16x16x32_f16((a), (b), (c), 0, 0, 0)

// problem constants
#define NB 2
#define NL 1024
#define ND 1024
#define NH 16
#define NHD 64
#define NP 2047
#define NBH (NB * NH)  // 32

// wave-synchronous LDS fence (wave-private LDS slices): no vmcnt drain
__device__ __forceinline__ void wave_sync_lds() {
  __builtin_amdgcn_sched_barrier(0);
  asm volatile("s_waitcnt lgkmcnt(0)" ::: "memory");
  __builtin_amdgcn_sched_barrier(0);
}

// async global->LDS, 16B per lane, wave-linear dest
__device__ __forceinline__ void gload16(const bf16* g, bf16* lds) {
  __builtin_amdgcn_global_load_lds((const __attribute__((address_space(1))) void*)g,
                                   (__attribute__((address_space(3))) void*)lds, 16, 0, 0);
}

// ---------------- kernel 0: split f32 -> hi/lo bf16 (used for X) ----------------
__global__ __launch_bounds__(256) void split_er_k(const float* __restrict__ er,
                                                  bf16* __restrict__ hi,
                                                  bf16* __restrict__ lo, int n) {
  int i = blockIdx.x * 256 + threadIdx.x;
  if (i < n) {
    float v = er[i];
    bf16 h = (bf16)v;
    hi[i] = h;
    lo[i] = (bf16)(v - (float)h);
  }
}

// ---------------- kernel 0c: pack Er into A-frag-major tiles (fp16, single term) ----------------
// epf index = ((h*128 + ob)*2 + half)*512 + lane*8 + e, row cl = lane&15,
// o = ob*16 - 1024 + cl, p = (o<=0)? -o : NP-o, d = half*32 + (lane>>4)*8 + e.
__global__ __launch_bounds__(256) void er_pack_k(const float* __restrict__ er,
                                                 f16* __restrict__ epf) {
  const int i = blockIdx.x * 256 + threadIdx.x;  // 2^21 total
  const int e = i & 7;
  const int lane = (i >> 3) & 63;
  const int half = (i >> 9) & 1;
  const int ob = (i >> 10) & 127;
  const int h = i >> 17;
  const int g = lane >> 4, cl = lane & 15;
  const int o = ob * 16 - 1024 + cl;
  const int p = (o <= 0) ? -o : (NP - o);
  const int d = half * 32 + g * 8 + e;
  epf[i] = (f16)er[(size_t)(h * NP + p) * NHD + d];
}

// ---------------- kernel 0b: transpose + split W [K][N] f32 -> WT [N][K] bf16 ----------------
__global__ __launch_bounds__(256) void trans_split_k(const float* __restrict__ W, int N, int K,
                                                     int n_lo, bf16* __restrict__ WT_h,
                                                     bf16* __restrict__ WT_l) {
  __shared__ float tile[64][68];
  const int n0 = blockIdx.x * 64, k0 = blockIdx.y * 64;
  const int t = threadIdx.x;
  const int rc = t & 15;
  const int rr0 = t >> 4;
#pragma unroll
  for (int i = 0; i < 4; ++i) {
    const int row = rr0 + i * 16;
    float4 v = *(const float4*)(W + (size_t)(k0 + row) * N + n0 + rc * 4);
    *(float4*)&tile[row][rc * 4] = v;
  }
  __syncthreads();
  const int n = t >> 2, kc = (t & 3) * 16;
  bf16x8 h0, h1, l0, l1;
#pragma unroll
  for (int e = 0; e < 8; ++e) {
    float v = tile[kc + e][n];
    bf16 hh = (bf16)v;
    h0[e] = hh;
    l0[e] = (bf16)(v - (float)hh);
  }
#pragma unroll
  for (int e = 0; e < 8; ++e) {
    float v = tile[kc + 8 + e][n];
    bf16 hh = (bf16)v;
    h1[e] = hh;
    l1[e] = (bf16)(v - (float)hh);
  }
  bf16* dst = WT_h + (size_t)(n0 + n) * K + k0 + kc;
  *(bf16x8*)dst = h0;
  *(bf16x8*)(dst + 8) = h1;
  if (WT_l != nullptr && (n0 + n) < n_lo) {
    bf16* dstl = WT_l + (size_t)(n0 + n) * K + k0 + kc;
    *(bf16x8*)dstl = l0;
    *(bf16x8*)(dstl + 8) = l1;
  }
}

// ---------------- kernel 1: QKV projection GEMM (R9 structure: 64x128, gload16, T2 swizzle) ----------------
// Grid: x = n-tile (24, fast -> mixes heavy Q blocks with lean KV blocks), y = m-tile (32).
__global__ __launch_bounds__(256) void qkv_gemm_k(const bf16* __restrict__ Xh,
                                                  const bf16* __restrict__ Xl,
                                                  const bf16* __restrict__ WTh,
                                                  const bf16* __restrict__ WTl,
                                                  const float* __restrict__ bias,
                                                  bf16* __restrict__ qh, f16* __restrict__ qf,
                                                  bf16* __restrict__ kp, bf16* __restrict__ vp) {
  __shared__ bf16 sAh[64 * 32], sAl[64 * 32], sBh[128 * 32], sBl[128 * 32];
  const int t = threadIdx.x;
  const int lane = t & 63;
  const int w = t >> 6;
  const int cl = lane & 15;
  const int g = lane >> 4;
  const int m0 = blockIdx.y * 64;
  const int n0 = blockIdx.x * 128;
  const bool isQ = (n0 < ND);

  const int arow = w * 16 + (lane >> 2);
  const int brow0 = w * 32 + (lane >> 2);
  const int scol = ((lane & 3) ^ ((lane >> 3) & 3)) * 8;  // T2 source swizzle
  const int rsw = (g ^ ((cl >> 1) & 3)) * 8;              // swizzled read col
  bf16* ldsA = &sAh[w * 512];
  bf16* ldsAl = &sAl[w * 512];
  bf16* ldsB0 = &sBh[w * 1024];
  bf16* ldsB1 = &sBh[w * 1024 + 512];
  bf16* ldsBl0 = &sBl[w * 1024];
  bf16* ldsBl1 = &sBl[w * 1024 + 512];

  f32x4 acc[4][2] = {};

  for (int k0 = 0; k0 < ND; k0 += 32) {
    gload16(Xh + (size_t)(m0 + arow) * ND + k0 + scol, ldsA);
    const bf16* gb0 = WTh + (size_t)(n0 + brow0) * ND + k0 + scol;
    gload16(gb0, ldsB0);
    gload16(gb0 + (size_t)16 * ND, ldsB1);
    if (isQ) {
      gload16(Xl + (size_t)(m0 + arow) * ND + k0 + scol, ldsAl);
      const bf16* gbl = WTl + (size_t)(n0 + brow0) * ND + k0 + scol;
      gload16(gbl, ldsBl0);
      gload16(gbl + (size_t)16 * ND, ldsBl1);
    }
    __syncthreads();

    bf16x8 ah[4], bh[2];
#pragma unroll
    for (int fm = 0; fm < 4; ++fm) ah[fm] = *(const bf16x8*)&sAh[(fm * 16 + cl) * 32 + rsw];
#pragma unroll
    for (int fn = 0; fn < 2; ++fn) bh[fn] = *(const bf16x8*)&sBh[(w * 32 + fn * 16 + cl) * 32 + rsw];
    if (isQ) {
      bf16x8 al[4], bl[2];
#pragma unroll
      for (int fm = 0; fm < 4; ++fm) al[fm] = *(const bf16x8*)&sAl[(fm * 16 + cl) * 32 + rsw];
#pragma unroll
      for (int fn = 0; fn < 2; ++fn) bl[fn] = *(const bf16x8*)&sBl[(w * 32 + fn * 16 + cl) * 32 + rsw];
#pragma unroll
      for (int fm = 0; fm < 4; ++fm)
#pragma unroll
        for (int fn = 0; fn < 2; ++fn) {
          acc[fm][fn] = MFMA16x16x32(ah[fm], bh[fn], acc[fm][fn]);
          acc[fm][fn] = MFMA16x16x32(ah[fm], bl[fn], acc[fm][fn]);
          acc[fm][fn] = MFMA16x16x32(al[fm], bh[fn], acc[fm][fn]);
        }
    } else {
#pragma unroll
      for (int fm = 0; fm < 4; ++fm)
#pragma unroll
        for (int fn = 0; fn < 2; ++fn)
          acc[fm][fn] = MFMA16x16x32(ah[fm], bh[fn], acc[fm][fn]);
    }
    __syncthreads();
  }

  // epilogue: bias + scatter into attention layouts (K/V frag-packed; Q as bf16-hi + f16-full)
#pragma unroll
  for (int fm = 0; fm < 4; ++fm) {
#pragma unroll
    for (int fn = 0; fn < 2; ++fn) {
#pragma unroll
      for (int reg = 0; reg < 4; ++reg) {
        const int gm = m0 + fm * 16 + g * 4 + reg;       // token row
        const int gn = n0 + w * 32 + fn * 16 + cl;       // qkv col
        float val = acc[fm][fn][reg] + bias[gn];
        const int bb = gm >> 10, lpos = gm & 1023;
        const int sec = gn >> 10, hc = gn & 1023;
        const int hh = hc >> 6, dd = hc & 63;
        const int bh = bb * NH + hh;
        if (sec == 0) {
          qh[(size_t)(bh * NL + lpos) * NHD + dd] = (bf16)val;
          qf[(size_t)(bh * NL + lpos) * NHD + dd] = (f16)val;
        } else if (sec == 1) {
          const size_t idx = ((size_t)((bh * 64 + (lpos >> 4)) * 2 + (dd >> 5))) * 512 +
                             ((((dd >> 3) & 3) << 4) + (lpos & 15)) * 8 + (dd & 7);
          kp[idx] = (bf16)val;
        } else {
          const size_t idx = ((size_t)(((bh * 16 + (lpos >> 6)) * 4 + (dd >> 4)) * 2 +
                                       ((lpos >> 5) & 1))) * 512 +
                             ((((lpos >> 3) & 3) << 4) + (dd & 15)) * 8 + (lpos & 7);
          vp[idx] = (bf16)val;
        }
      }
    }
  }
}

// ---------------- kernel 2: attention, v9 (fp16 single-term E bias) ----------------
__global__ __launch_bounds__(256) void attn_k(const bf16* __restrict__ qh, const f16* __restrict__ qf,
                                              const bf16* __restrict__ kp, const bf16* __restrict__ vp,
                                              const f16* __restrict__ epf,
                                              bf16* __restrict__ ao) {
  __shared__ float s_lds[4][16][67];
  __shared__ bf16 p_lds[4][16][72];
  __shared__ float mb[4][16], lbuf[4][16], linv[16];

  const int t = threadIdx.x;
  const int w = t >> 6;
  const int lane = t & 63;
  const int cl = lane & 15;
  const int g = lane >> 4;

  const int n = blockIdx.x;
  const int xcd = n & 7, idx = n >> 3;
  const int bh = (xcd << 2) | (idx >> 6);
  const int itile = 63 - (idx & 63);
  const int i0 = itile * 16;
  const int h = bh & (NH - 1);
  const int nchunks = (itile >> 2) + 1;

  const bf16* qhb = qh + (size_t)(bh * NL + i0 + cl) * NHD + g * 8;
  const f16* qfb = qf + (size_t)(bh * NL + i0 + cl) * NHD + g * 8;
  const bf16x8 q_h0 = *(const bf16x8*)qhb;
  const bf16x8 q_h1 = *(const bf16x8*)(qhb + 32);
  const f16x8 q_f0 = *(const f16x8*)qfb;
  const f16x8 q_f1 = *(const f16x8*)(qfb + 32);

  f32x4 acc_o[4] = {};
  float m_s = -3e38f, l_s = 0.0f;

  for (int jc = w; jc < nchunks; jc += 4) {
    const int j0 = jc * 64;
    const int delta = i0 - j0;

    // ---- V fragments (contiguous 1KB streams) ----
    const bf16* vbase = vp + ((size_t)(bh * 16 + (j0 >> 6)) * 8) * 512 + lane * 8;
    bf16x8 vf[4][2];
#pragma unroll
    for (int t4 = 0; t4 < 4; ++t4) {
      vf[t4][0] = *(const bf16x8*)(vbase + (t4 * 2 + 0) * 512);
      vf[t4][1] = *(const bf16x8*)(vbase + (t4 * 2 + 1) * 512);
    }

    // ---- S = Q K^T (bf16 hi) ----
    const bf16* kbase = kp + ((size_t)(bh * 64 + (j0 >> 4)) * 2) * 512 + lane * 8;
    f32x4 acc_s[4];
    __builtin_amdgcn_s_setprio(1);
#pragma unroll
    for (int jn = 0; jn < 4; ++jn) {
      bf16x8 kf0 = *(const bf16x8*)(kbase + (jn * 2 + 0) * 512);
      bf16x8 kf1 = *(const bf16x8*)(kbase + (jn * 2 + 1) * 512);
      f32x4 a = {};
      a = MFMA16x16x32(q_h0, kf0, a);
      a = MFMA16x16x32(q_h1, kf1, a);
      acc_s[jn] = a;
    }

    // ---- bias: 5 Er tiles, fp16 single-term ----
    const int ob0 = (delta >> 4) + 60;
    const f16* ebase = epf + ((size_t)(h * 128 + ob0) * 2) * 512 + lane * 8;
    f32x4 acc_e[5];
#pragma unroll
    for (int tt = 0; tt < 5; ++tt) {
      f16x8 ef0 = *(const f16x8*)(ebase + (tt * 2 + 0) * 512);
      f16x8 ef1 = *(const f16x8*)(ebase + (tt * 2 + 1) * 512);
      f32x4 c = {};
      c = MFMA16x16x32F(q_f0, ef0, c);
      c = MFMA16x16x32F(q_f1, ef1, c);
      acc_e[tt] = c;
    }
    __builtin_amdgcn_s_setprio(0);

    // ---- in-register diagonal gather of E into S; spill combined to LDS ----
#pragma unroll
    for (int reg = 0; reg < 4; ++reg) {
      const int r = g * 4 + reg;
      const int src = (g << 4) | ((r - cl) & 15);
      const bool ge = (r >= cl);
#pragma unroll
      for (int jn = 0; jn < 4; ++jn) {
        float e_hi = __shfl(acc_e[4 - jn][reg], src);
        float e_lo = __shfl(acc_e[3 - jn][reg], src);
        s_lds[w][r][jn * 16 + cl] = fmaf(acc_s[jn][reg], 0.125f, ge ? e_hi : e_lo);
      }
    }
    wave_sync_lds();

    // ---- online softmax; lane handles row=cl, cols g*16..g*16+15 ----
    float sv[16];
    float tmax = -3e38f;
#pragma unroll
    for (int cc = 0; cc < 16; ++cc) {
      const int c = g * 16 + cc;
      float v = s_lds[w][cl][c];
      if (c > delta + cl) v = -3e38f;
      sv[cc] = v;
      tmax = fmaxf(tmax, v);
    }
    tmax = fmaxf(tmax, __shfl_xor(tmax, 16));
    tmax = fmaxf(tmax, __shfl_xor(tmax, 32));
    const float m_new = fmaxf(m_s, tmax);
    const float fsc = __builtin_amdgcn_exp2f((m_s - m_new) * 1.44269504f);
    float psum = 0.0f;
    bf16x8 plo, phi;
#pragma unroll
    for (int cc = 0; cc < 16; ++cc) {
      float pv = __builtin_amdgcn_exp2f((sv[cc] - m_new) * 1.44269504f);
      psum += pv;
      if (cc < 8) plo[cc & 7] = (bf16)pv;
      else        phi[cc & 7] = (bf16)pv;
    }
    psum += __shfl_xor(psum, 16);
    psum += __shfl_xor(psum, 32);
    l_s = l_s * fsc + psum;
    m_s = m_new;

    *(bf16x8*)&p_lds[w][cl][g * 16] = plo;
    *(bf16x8*)&p_lds[w][cl][g * 16 + 8] = phi;
    wave_sync_lds();
    bf16x8 pf0 = *(const bf16x8*)&p_lds[w][cl][g * 8];
    bf16x8 pf1 = *(const bf16x8*)&p_lds[w][cl][32 + g * 8];

    float fr[4];
#pragma unroll
    for (int reg = 0; reg < 4; ++reg) fr[reg] = __shfl(fsc, g * 4 + reg);
#pragma unroll
    for (int t4 = 0; t4 < 4; ++t4) {
#pragma unroll
      for (int reg = 0; reg < 4; ++reg) acc_o[t4][reg] *= fr[reg];
    }
    __builtin_amdgcn_s_setprio(1);
#pragma unroll
    for (int t4 = 0; t4 < 4; ++t4) {
      acc_o[t4] = MFMA16x16x32(pf0, vf[t4][0], acc_o[t4]);
      acc_o[t4] = MFMA16x16x32(pf1, vf[t4][1], acc_o[t4]);
    }
    __builtin_amdgcn_s_setprio(0);
  }

  // ---- flash-merge the 4 waves' partials (s_lds reused as obuf) ----
  if (lane < 16) {
    mb[w][lane] = m_s;
    lbuf[w][lane] = l_s;
  }
  __syncthreads();
  const float M = fmaxf(fmaxf(mb[0][cl], mb[1][cl]), fmaxf(mb[2][cl], mb[3][cl]));
  const float sc = __builtin_amdgcn_exp2f((m_s - M) * 1.44269504f);
  float Lt = 0.0f;
#pragma unroll
  for (int ww = 0; ww < 4; ++ww)
    Lt += lbuf[ww][cl] * __builtin_amdgcn_exp2f((mb[ww][cl] - M) * 1.44269504f);
  if (w == 0 && lane < 16) linv[lane] = 1.0f / Lt;
  float fr2[4];
#pragma unroll
  for (int reg = 0; reg < 4; ++reg) fr2[reg] = __shfl(sc, g * 4 + reg);
#pragma unroll
  for (int t4 = 0; t4 < 4; ++t4) {
#pragma unroll
    for (int reg = 0; reg < 4; ++reg)
      s_lds[w][g * 4 + reg][t4 * 16 + cl] = acc_o[t4][reg] * fr2[reg];
  }
  __syncthreads();
  const int bb = bh >> 4;
#pragma unroll
  for (int rep = 0; rep < 4; ++rep) {
    const int o_ = t + rep * 256;
    const int r = o_ >> 6, c = o_ & 63;
    float s = s_lds[0][r][c] + s_lds[1][r][c] + s_lds[2][r][c] + s_lds[3][r][c];
    ao[(size_t)(bb * NL + i0 + r) * ND + h * NHD + c] = (bf16)(s * linv[r]);
  }
}

// ---------------- kernel 3: output projection (64x128 tile, gload_lds, T2 swizzle) ----------------
__global__ __launch_bounds__(256) void out_gemm_k(const bf16* __restrict__ A,
                                                  const bf16* __restrict__ WT,
                                                  const float* __restrict__ bias,
                                                  float* __restrict__ out) {
  __shared__ bf16 sA[64 * 32], sB[128 * 32];
  const int t = threadIdx.x;
  const int lane = t & 63, w = t >> 6;
  const int cl = lane & 15, g = lane >> 4;
  const int m0 = blockIdx.x * 64;
  const int n0 = blockIdx.y * 128;

  const int arow = w * 16 + (lane >> 2);
  const int brow0 = w * 32 + (lane >> 2);
  const int scol = ((lane & 3) ^ ((lane >> 3) & 3)) * 8;
  const int rsw = (g ^ ((cl >> 1) & 3)) * 8;
  bf16* ldsA = &sA[w * 512];
  bf16* ldsB0 = &sB[w * 1024];
  bf16* ldsB1 = &sB[w * 1024 + 512];

  f32x4 acc[4][2] = {};

  for (int k0 = 0; k0 < ND; k0 += 32) {
    gload16(A + (size_t)(m0 + arow) * ND + k0 + scol, ldsA);
    const bf16* gb0 = WT + (size_t)(n0 + brow0) * ND + k0 + scol;
    gload16(gb0, ldsB0);
    gload16(gb0 + (size_t)16 * ND, ldsB1);
    __syncthreads();
    bf16x8 ah[4], bh[2];
#pragma unroll
    for (int fm = 0; fm < 4; ++fm) ah[fm] = *(const bf16x8*)&sA[(fm * 16 + cl) * 32 + rsw];
#pragma unroll
    for (int fn = 0; fn < 2; ++fn) bh[fn] = *(const bf16x8*)&sB[(w * 32 + fn * 16 + cl) * 32 + rsw];
#pragma unroll
    for (int fm = 0; fm < 4; ++fm)
#pragma unroll
      for (int fn = 0; fn < 2; ++fn)
        acc[fm][fn] = MFMA16x16x32(ah[fm], bh[fn], acc[fm][fn]);
    __syncthreads();
  }
#pragma unroll
  for (int fm = 0; fm < 4; ++fm) {
#pragma unroll
    for (int fn = 0; fn < 2; ++fn) {
#pragma unroll
      for (int reg = 0; reg < 4; ++reg) {
        const int gm = m0 + fm * 16 + g * 4 + reg;
        const int gn = n0 + w * 32 + fn * 16 + cl;
        out[(size_t)gm * ND + gn] = acc[fm][fn][reg] + bias[gn];
      }
    }
  }
}

extern "C" void kernel_launch(void* const* d_in, const int* in_sizes, int n_in,
                              void* d_out, int out_size, void* d_ws, size_t ws_size,
                              hipStream_t stream) {
  (void)in_sizes; (void)n_in; (void)out_size; (void)ws_size;
  const float* x = (const float*)d_in[0];
  // d_in[1] = causal mask — structural (triu k=1), computed inline
  const float* Wqkv = (const float*)d_in[2];
  const float* bqkv = (const float*)d_in[3];
  const float* Wo = (const float*)d_in[4];
  const float* bo = (const float*)d_in[5];
  const float* Er = (const float*)d_in[6];

  char* ws = (char*)d_ws;
  size_t off = 0;
  auto take = [&](size_t bytes) {
    char* p = ws + off;
    off += (bytes + 255) & ~(size_t)255;
    return p;
  };
  const size_t qkN = (size_t)NBH * NL * NHD;       // 2,097,152
  const size_t xN = (size_t)NB * NL * ND;          // 2,097,152
  const size_t erpN = (size_t)NH * 128 * 2 * 512;  // 2,097,152
  f16*  epf = (f16*)take(erpN * 2);
  bf16* qhw = (bf16*)take(qkN * 2);
  f16*  qfw = (f16*)take(qkN * 2);
  bf16* kpw = (bf16*)take(qkN * 2);    // K frag-packed
  bf16* vpw = (bf16*)take(qkN * 2);    // V frag-packed
  bf16* wqkvth = (bf16*)take((size_t)3 * ND * ND * 2);  // [3072][1024]
  bf16* wqkvtl = (bf16*)take((size_t)ND * ND * 2);      // [1024][1024] (Q section only)
  bf16* woth   = (bf16*)take((size_t)ND * ND * 2);      // [1024][1024]
  bf16* xsh    = (bf16*)take(xN * 2);                   // X hi
  bf16* xsl    = (bf16*)take(xN * 2);                   // X lo
  bf16* aow = wqkvth;  // alias: wqkvth dead after qkv_gemm, aow born in attn

  er_pack_k<<<(int)(erpN / 256), 256, 0, stream>>>(Er, epf);
  split_er_k<<<(int)((xN + 255) / 256), 256, 0, stream>>>(x, xsh, xsl, (int)xN);
  trans_split_k<<<dim3(48, 16), 256, 0, stream>>>(Wqkv, 3 * ND, ND, ND, wqkvth, wqkvtl);
  trans_split_k<<<dim3(16, 16), 256, 0, stream>>>(Wo, ND, ND, 0, woth, nullptr);
  qkv_gemm_k<<<dim3(24, 32), 256, 0, stream>>>(xsh, xsl, wqkvth, wqkvtl, bqkv,
                                               qhw, qfw, kpw, vpw);
  attn_k<<<2048, 256, 0, stream>>>(qhw, qfw, kpw, vpw, epf, aow);
  out_gemm_k<<<dim3(32, 8), 256, 0, stream>>>(aow, woth, bo, (float*)d_out);
}

// Round 12
// 94.483 us; speedup vs baseline: 1.3281x; 1.2414x over previous
//
#include <hip/hip_runtime.h>

typedef _Float16 f16;
typedef _Float16 f16x8 __attribute__((ext_vector_type(8)));
typedef float f32x4 __attribute__((ext_vector_type(4)));

static_assert(sizeof(f16x8) == 16, "f16x8 must be 16B");

#define MFMA16x16x32F(a, b, c) __builtin_amdgcn_mfma_f32_16x16x32_f16((a), (b), (c), 0, 0, 0)

// problem constants
#define NB 2
#define NL 1024
#define ND 1024
#define NH 16
#define NHD 64
#define NP 2047
#define NBH (NB * NH)  // 32

// wave-synchronous LDS fence (wave-private LDS slices): no vmcnt drain
__device__ __forceinline__ void wave_sync_lds() {
  __builtin_amdgcn_sched_barrier(0);
  asm volatile("s_waitcnt lgkmcnt(0)" ::: "memory");
  __builtin_amdgcn_sched_barrier(0);
}

// async global->LDS, 16B per lane, wave-linear dest
__device__ __forceinline__ void gload16(const f16* g, f16* lds) {
  __builtin_amdgcn_global_load_lds((const __attribute__((address_space(1))) void*)g,
                                   (__attribute__((address_space(3))) void*)lds, 16, 0, 0);
}

// ---------------- kernel 0: cast f32 -> f16 (X) ----------------
__global__ __launch_bounds__(256) void cast16_k(const float* __restrict__ in,
                                                f16* __restrict__ out, int n) {
  int i = blockIdx.x * 256 + threadIdx.x;
  if (i < n) out[i] = (f16)in[i];
}

// ---------------- kernel 0c: pack Er into B-frag-major tiles (f16) ----------------
// epf index = ((h*128 + ob)*2 + half)*512 + lane*8 + e, row cl = lane&15,
// o = ob*16 - 1024 + cl, p = (o<=0)? -o : NP-o, d = half*32 + (lane>>4)*8 + e.
__global__ __launch_bounds__(256) void er_pack_k(const float* __restrict__ er,
                                                 f16* __restrict__ epf) {
  const int i = blockIdx.x * 256 + threadIdx.x;  // 2^21 total
  const int e = i & 7;
  const int lane = (i >> 3) & 63;
  const int half = (i >> 9) & 1;
  const int ob = (i >> 10) & 127;
  const int h = i >> 17;
  const int g = lane >> 4, cl = lane & 15;
  const int o = ob * 16 - 1024 + cl;
  const int p = (o <= 0) ? -o : (NP - o);
  const int d = half * 32 + g * 8 + e;
  epf[i] = (f16)er[(size_t)(h * NP + p) * NHD + d];
}

// ---------------- kernel 0b: transpose W [K][N] f32 -> WT [N][K] f16 ----------------
__global__ __launch_bounds__(256) void trans_f16_k(const float* __restrict__ W, int N, int K,
                                                   f16* __restrict__ WT) {
  __shared__ float tile[64][68];
  const int n0 = blockIdx.x * 64, k0 = blockIdx.y * 64;
  const int t = threadIdx.x;
  const int rc = t & 15;
  const int rr0 = t >> 4;
#pragma unroll
  for (int i = 0; i < 4; ++i) {
    const int row = rr0 + i * 16;
    float4 v = *(const float4*)(W + (size_t)(k0 + row) * N + n0 + rc * 4);
    *(float4*)&tile[row][rc * 4] = v;
  }
  __syncthreads();
  const int n = t >> 2, kc = (t & 3) * 16;
  f16x8 h0, h1;
#pragma unroll
  for (int e = 0; e < 8; ++e) h0[e] = (f16)tile[kc + e][n];
#pragma unroll
  for (int e = 0; e < 8; ++e) h1[e] = (f16)tile[kc + 8 + e][n];
  f16* dst = WT + (size_t)(n0 + n) * K + k0 + kc;
  *(f16x8*)dst = h0;
  *(f16x8*)(dst + 8) = h1;
}

// ---------------- kernel 1: QKV projection GEMM (uniform f16, 64x128 tile, BK=32) ----------------
// Grid: x = n-tile (24, fast), y = m-tile (32). T2 source swizzle on staging.
__global__ __launch_bounds__(256) void qkv_gemm_k(const f16* __restrict__ Xf,
                                                  const f16* __restrict__ WT,
                                                  const float* __restrict__ bias,
                                                  f16* __restrict__ qf,
                                                  f16* __restrict__ kp, f16* __restrict__ vp) {
  __shared__ f16 sA[64 * 32], sB[128 * 32];
  const int t = threadIdx.x;
  const int lane = t & 63;
  const int w = t >> 6;
  const int cl = lane & 15;
  const int g = lane >> 4;
  const int m0 = blockIdx.y * 64;
  const int n0 = blockIdx.x * 128;

  const int arow = w * 16 + (lane >> 2);
  const int brow0 = w * 32 + (lane >> 2);
  const int scol = ((lane & 3) ^ ((lane >> 3) & 3)) * 8;  // T2 source swizzle
  const int rsw = (g ^ ((cl >> 1) & 3)) * 8;              // swizzled read col
  f16* ldsA = &sA[w * 512];
  f16* ldsB0 = &sB[w * 1024];
  f16* ldsB1 = &sB[w * 1024 + 512];

  f32x4 acc[4][2] = {};

  for (int k0 = 0; k0 < ND; k0 += 32) {
    gload16(Xf + (size_t)(m0 + arow) * ND + k0 + scol, ldsA);
    const f16* gb0 = WT + (size_t)(n0 + brow0) * ND + k0 + scol;
    gload16(gb0, ldsB0);
    gload16(gb0 + (size_t)16 * ND, ldsB1);
    __syncthreads();

    f16x8 ah[4], bh[2];
#pragma unroll
    for (int fm = 0; fm < 4; ++fm) ah[fm] = *(const f16x8*)&sA[(fm * 16 + cl) * 32 + rsw];
#pragma unroll
    for (int fn = 0; fn < 2; ++fn) bh[fn] = *(const f16x8*)&sB[(w * 32 + fn * 16 + cl) * 32 + rsw];
#pragma unroll
    for (int fm = 0; fm < 4; ++fm)
#pragma unroll
      for (int fn = 0; fn < 2; ++fn)
        acc[fm][fn] = MFMA16x16x32F(ah[fm], bh[fn], acc[fm][fn]);
    __syncthreads();
  }

  // epilogue: bias + scatter into attention layouts (all f16)
#pragma unroll
  for (int fm = 0; fm < 4; ++fm) {
#pragma unroll
    for (int fn = 0; fn < 2; ++fn) {
#pragma unroll
      for (int reg = 0; reg < 4; ++reg) {
        const int gm = m0 + fm * 16 + g * 4 + reg;       // token row
        const int gn = n0 + w * 32 + fn * 16 + cl;       // qkv col
        float val = acc[fm][fn][reg] + bias[gn];
        const int bb = gm >> 10, lpos = gm & 1023;
        const int sec = gn >> 10, hc = gn & 1023;
        const int hh = hc >> 6, dd = hc & 63;
        const int bh = bb * NH + hh;
        if (sec == 0) {
          qf[(size_t)(bh * NL + lpos) * NHD + dd] = (f16)val;
        } else if (sec == 1) {
          // K packed (B-frag): tile jt=lpos>>4, frag f=dd>>5, lane=((dd>>3)&3)*16+(lpos&15), e=dd&7
          const size_t idx = ((size_t)((bh * 64 + (lpos >> 4)) * 2 + (dd >> 5))) * 512 +
                             ((((dd >> 3) & 3) << 4) + (lpos & 15)) * 8 + (dd & 7);
          kp[idx] = (f16)val;
        } else {
          // V packed (B-frag): chunk jc=lpos>>6, t4=dd>>4, half=(lpos>>5)&1,
          // lane=((lpos>>3)&3)*16+(dd&15), e=lpos&7
          const size_t idx = ((size_t)(((bh * 16 + (lpos >> 6)) * 4 + (dd >> 4)) * 2 +
                                       ((lpos >> 5) & 1))) * 512 +
                             ((((lpos >> 3) & 3) << 4) + (dd & 15)) * 8 + (lpos & 7);
          vp[idx] = (f16)val;
        }
      }
    }
  }
}

// ---------------- kernel 2: attention, v10 (all-f16 fragments) ----------------
__global__ __launch_bounds__(256) void attn_k(const f16* __restrict__ qf,
                                              const f16* __restrict__ kp, const f16* __restrict__ vp,
                                              const f16* __restrict__ epf,
                                              f16* __restrict__ ao) {
  __shared__ float s_lds[4][16][67];
  __shared__ f16 p_lds[4][16][72];
  __shared__ float mb[4][16], lbuf[4][16], linv[16];

  const int t = threadIdx.x;
  const int w = t >> 6;
  const int lane = t & 63;
  const int cl = lane & 15;
  const int g = lane >> 4;

  const int n = blockIdx.x;
  const int xcd = n & 7, idx = n >> 3;
  const int bh = (xcd << 2) | (idx >> 6);
  const int itile = 63 - (idx & 63);
  const int i0 = itile * 16;
  const int h = bh & (NH - 1);
  const int nchunks = (itile >> 2) + 1;

  const f16* qfb = qf + (size_t)(bh * NL + i0 + cl) * NHD + g * 8;
  const f16x8 q_f0 = *(const f16x8*)qfb;
  const f16x8 q_f1 = *(const f16x8*)(qfb + 32);

  f32x4 acc_o[4] = {};
  float m_s = -3e38f, l_s = 0.0f;

  for (int jc = w; jc < nchunks; jc += 4) {
    const int j0 = jc * 64;
    const int delta = i0 - j0;

    // ---- V fragments (contiguous 1KB streams) ----
    const f16* vbase = vp + ((size_t)(bh * 16 + (j0 >> 6)) * 8) * 512 + lane * 8;
    f16x8 vf[4][2];
#pragma unroll
    for (int t4 = 0; t4 < 4; ++t4) {
      vf[t4][0] = *(const f16x8*)(vbase + (t4 * 2 + 0) * 512);
      vf[t4][1] = *(const f16x8*)(vbase + (t4 * 2 + 1) * 512);
    }

    // ---- S = Q K^T ----
    const f16* kbase = kp + ((size_t)(bh * 64 + (j0 >> 4)) * 2) * 512 + lane * 8;
    f32x4 acc_s[4];
    __builtin_amdgcn_s_setprio(1);
#pragma unroll
    for (int jn = 0; jn < 4; ++jn) {
      f16x8 kf0 = *(const f16x8*)(kbase + (jn * 2 + 0) * 512);
      f16x8 kf1 = *(const f16x8*)(kbase + (jn * 2 + 1) * 512);
      f32x4 a = {};
      a = MFMA16x16x32F(q_f0, kf0, a);
      a = MFMA16x16x32F(q_f1, kf1, a);
      acc_s[jn] = a;
    }

    // ---- bias: 5 Er tiles ----
    const int ob0 = (delta >> 4) + 60;
    const f16* ebase = epf + ((size_t)(h * 128 + ob0) * 2) * 512 + lane * 8;
    f32x4 acc_e[5];
#pragma unroll
    for (int tt = 0; tt < 5; ++tt) {
      f16x8 ef0 = *(const f16x8*)(ebase + (tt * 2 + 0) * 512);
      f16x8 ef1 = *(const f16x8*)(ebase + (tt * 2 + 1) * 512);
      f32x4 c = {};
      c = MFMA16x16x32F(q_f0, ef0, c);
      c = MFMA16x16x32F(q_f1, ef1, c);
      acc_e[tt] = c;
    }
    __builtin_amdgcn_s_setprio(0);

    // ---- in-register diagonal gather of E into S; spill combined to LDS ----
#pragma unroll
    for (int reg = 0; reg < 4; ++reg) {
      const int r = g * 4 + reg;
      const int src = (g << 4) | ((r - cl) & 15);
      const bool ge = (r >= cl);
#pragma unroll
      for (int jn = 0; jn < 4; ++jn) {
        float e_hi = __shfl(acc_e[4 - jn][reg], src);
        float e_lo = __shfl(acc_e[3 - jn][reg], src);
        s_lds[w][r][jn * 16 + cl] = fmaf(acc_s[jn][reg], 0.125f, ge ? e_hi : e_lo);
      }
    }
    wave_sync_lds();

    // ---- online softmax; lane handles row=cl, cols g*16..g*16+15 ----
    float sv[16];
    float tmax = -3e38f;
#pragma unroll
    for (int cc = 0; cc < 16; ++cc) {
      const int c = g * 16 + cc;
      float v = s_lds[w][cl][c];
      if (c > delta + cl) v = -3e38f;
      sv[cc] = v;
      tmax = fmaxf(tmax, v);
    }
    tmax = fmaxf(tmax, __shfl_xor(tmax, 16));
    tmax = fmaxf(tmax, __shfl_xor(tmax, 32));
    const float m_new = fmaxf(m_s, tmax);
    const float fsc = __builtin_amdgcn_exp2f((m_s - m_new) * 1.44269504f);
    float psum = 0.0f;
    f16x8 plo, phi;
#pragma unroll
    for (int cc = 0; cc < 16; ++cc) {
      float pv = __builtin_amdgcn_exp2f((sv[cc] - m_new) * 1.44269504f);
      psum += pv;
      if (cc < 8) plo[cc & 7] = (f16)pv;
      else        phi[cc & 7] = (f16)pv;
    }
    psum += __shfl_xor(psum, 16);
    psum += __shfl_xor(psum, 32);
    l_s = l_s * fsc + psum;
    m_s = m_new;

    *(f16x8*)&p_lds[w][cl][g * 16] = plo;
    *(f16x8*)&p_lds[w][cl][g * 16 + 8] = phi;
    wave_sync_lds();
    f16x8 pf0 = *(const f16x8*)&p_lds[w][cl][g * 8];
    f16x8 pf1 = *(const f16x8*)&p_lds[w][cl][32 + g * 8];

    float fr[4];
#pragma unroll
    for (int reg = 0; reg < 4; ++reg) fr[reg] = __shfl(fsc, g * 4 + reg);
#pragma unroll
    for (int t4 = 0; t4 < 4; ++t4) {
#pragma unroll
      for (int reg = 0; reg < 4; ++reg) acc_o[t4][reg] *= fr[reg];
    }
    __builtin_amdgcn_s_setprio(1);
#pragma unroll
    for (int t4 = 0; t4 < 4; ++t4) {
      acc_o[t4] = MFMA16x16x32F(pf0, vf[t4][0], acc_o[t4]);
      acc_o[t4] = MFMA16x16x32F(pf1, vf[t4][1], acc_o[t4]);
    }
    __builtin_amdgcn_s_setprio(0);
  }

  // ---- flash-merge the 4 waves' partials (s_lds reused as obuf) ----
  if (lane < 16) {
    mb[w][lane] = m_s;
    lbuf[w][lane] = l_s;
  }
  __syncthreads();
  const float M = fmaxf(fmaxf(mb[0][cl], mb[1][cl]), fmaxf(mb[2][cl], mb[3][cl]));
  const float sc = __builtin_amdgcn_exp2f((m_s - M) * 1.44269504f);
  float Lt = 0.0f;
#pragma unroll
  for (int ww = 0; ww < 4; ++ww)
    Lt += lbuf[ww][cl] * __builtin_amdgcn_exp2f((mb[ww][cl] - M) * 1.44269504f);
  if (w == 0 && lane < 16) linv[lane] = 1.0f / Lt;
  float fr2[4];
#pragma unroll
  for (int reg = 0; reg < 4; ++reg) fr2[reg] = __shfl(sc, g * 4 + reg);
#pragma unroll
  for (int t4 = 0; t4 < 4; ++t4) {
#pragma unroll
    for (int reg = 0; reg < 4; ++reg)
      s_lds[w][g * 4 + reg][t4 * 16 + cl] = acc_o[t4][reg] * fr2[reg];
  }
  __syncthreads();
  const int bb = bh >> 4;
#pragma unroll
  for (int rep = 0; rep < 4; ++rep) {
    const int o_ = t + rep * 256;
    const int r = o_ >> 6, c = o_ & 63;
    float s = s_lds[0][r][c] + s_lds[1][r][c] + s_lds[2][r][c] + s_lds[3][r][c];
    ao[(size_t)(bb * NL + i0 + r) * ND + h * NHD + c] = (f16)(s * linv[r]);
  }
}

// ---------------- kernel 3: output projection (f16, 64x128 tile, gload_lds, T2 swizzle) ----------------
__global__ __launch_bounds__(256) void out_gemm_k(const f16* __restrict__ A,
                                                  const f16* __restrict__ WT,
                                                  const float* __restrict__ bias,
                                                  float* __restrict__ out) {
  __shared__ f16 sA[64 * 32], sB[128 * 32];
  const int t = threadIdx.x;
  const int lane = t & 63, w = t >> 6;
  const int cl = lane & 15, g = lane >> 4;
  const int m0 = blockIdx.x * 64;
  const int n0 = blockIdx.y * 128;

  const int arow = w * 16 + (lane >> 2);
  const int brow0 = w * 32 + (lane >> 2);
  const int scol = ((lane & 3) ^ ((lane >> 3) & 3)) * 8;
  const int rsw = (g ^ ((cl >> 1) & 3)) * 8;
  f16* ldsA = &sA[w * 512];
  f16* ldsB0 = &sB[w * 1024];
  f16* ldsB1 = &sB[w * 1024 + 512];

  f32x4 acc[4][2] = {};

  for (int k0 = 0; k0 < ND; k0 += 32) {
    gload16(A + (size_t)(m0 + arow) * ND + k0 + scol, ldsA);
    const f16* gb0 = WT + (size_t)(n0 + brow0) * ND + k0 + scol;
    gload16(gb0, ldsB0);
    gload16(gb0 + (size_t)16 * ND, ldsB1);
    __syncthreads();
    f16x8 ah[4], bh[2];
#pragma unroll
    for (int fm = 0; fm < 4; ++fm) ah[fm] = *(const f16x8*)&sA[(fm * 16 + cl) * 32 + rsw];
#pragma unroll
    for (int fn = 0; fn < 2; ++fn) bh[fn] = *(const f16x8*)&sB[(w * 32 + fn * 16 + cl) * 32 + rsw];
#pragma unroll
    for (int fm = 0; fm < 4; ++fm)
#pragma unroll
      for (int fn = 0; fn < 2; ++fn)
        acc[fm][fn] = MFMA16x16x32F(ah[fm], bh[fn], acc[fm][fn]);
    __syncthreads();
  }
#pragma unroll
  for (int fm = 0; fm < 4; ++fm) {
#pragma unroll
    for (int fn = 0; fn < 2; ++fn) {
#pragma unroll
      for (int reg = 0; reg < 4; ++reg) {
        const int gm = m0 + fm * 16 + g * 4 + reg;
        const int gn = n0 + w * 32 + fn * 16 + cl;
        out[(size_t)gm * ND + gn] = acc[fm][fn][reg] + bias[gn];
      }
    }
  }
}

extern "C" void kernel_launch(void* const* d_in, const int* in_sizes, int n_in,
                              void* d_out, int out_size, void* d_ws, size_t ws_size,
                              hipStream_t stream) {
  (void)in_sizes; (void)n_in; (void)out_size; (void)ws_size;
  const float* x = (const float*)d_in[0];
  // d_in[1] = causal mask — structural (triu k=1), computed inline
  const float* Wqkv = (const float*)d_in[2];
  const float* bqkv = (const float*)d_in[3];
  const float* Wo = (const float*)d_in[4];
  const float* bo = (const float*)d_in[5];
  const float* Er = (const float*)d_in[6];

  char* ws = (char*)d_ws;
  size_t off = 0;
  auto take = [&](size_t bytes) {
    char* p = ws + off;
    off += (bytes + 255) & ~(size_t)255;
    return p;
  };
  const size_t qkN = (size_t)NBH * NL * NHD;       // 2,097,152
  const size_t xN = (size_t)NB * NL * ND;          // 2,097,152
  const size_t erpN = (size_t)NH * 128 * 2 * 512;  // 2,097,152
  f16* epf = (f16*)take(erpN * 2);
  f16* qfw = (f16*)take(qkN * 2);
  f16* kpw = (f16*)take(qkN * 2);    // K frag-packed
  f16* vpw = (f16*)take(qkN * 2);    // V frag-packed
  f16* wqkvt = (f16*)take((size_t)3 * ND * ND * 2);  // [3072][1024]
  f16* wot   = (f16*)take((size_t)ND * ND * 2);      // [1024][1024]
  f16* xf    = (f16*)take(xN * 2);                   // X f16
  f16* aow = wqkvt;  // alias: wqkvt dead after qkv_gemm, aow born in attn

  er_pack_k<<<(int)(erpN / 256), 256, 0, stream>>>(Er, epf);
  cast16_k<<<(int)((xN + 255) / 256), 256, 0, stream>>>(x, xf, (int)xN);
  trans_f16_k<<<dim3(48, 16), 256, 0, stream>>>(Wqkv, 3 * ND, ND, wqkvt);
  trans_f16_k<<<dim3(16, 16), 256, 0, stream>>>(Wo, ND, ND, wot);
  qkv_gemm_k<<<dim3(24, 32), 256, 0, stream>>>(xf, wqkvt, bqkv, qfw, kpw, vpw);
  attn_k<<<2048, 256, 0, stream>>>(qfw, kpw, vpw, epf, aow);
  out_gemm_k<<<dim3(32, 8), 256, 0, stream>>>(aow, wot, bo, (float*)d_out);
}

// Round 13
// 87.124 us; speedup vs baseline: 1.4402x; 1.0845x over previous
//
#include <hip/hip_runtime.h>

typedef _Float16 f16;
typedef _Float16 f16x8 __attribute__((ext_vector_type(8)));
typedef float f32x4 __attribute__((ext_vector_type(4)));

static_assert(sizeof(f16x8) == 16, "f16x8 must be 16B");

#define MFMA16x16x32F(a, b, c) __builtin_amdgcn_mfma_f32_16x16x32_f16((a), (b), (c), 0, 0, 0)

// problem constants
#define NB 2
#define NL 1024
#define ND 1024
#define NH 16
#define NHD 64
#define NP 2047
#define NBH (NB * NH)  // 32

// wave-synchronous LDS fence (wave-private LDS slices): no vmcnt drain
__device__ __forceinline__ void wave_sync_lds() {
  __builtin_amdgcn_sched_barrier(0);
  asm volatile("s_waitcnt lgkmcnt(0)" ::: "memory");
  __builtin_amdgcn_sched_barrier(0);
}

// async global->LDS, 16B per lane, wave-linear dest
__device__ __forceinline__ void gload16(const f16* g, f16* lds) {
  __builtin_amdgcn_global_load_lds((const __attribute__((address_space(1))) void*)g,
                                   (__attribute__((address_space(3))) void*)lds, 16, 0, 0);
}

// ---------------- kernel 0: fused prep — Er frag-pack + X cast (f16) ----------------
// blocks [0, 8192): er_pack; blocks [8192, 16384): X cast.
__global__ __launch_bounds__(256) void prep_pack_k(const float* __restrict__ er,
                                                   f16* __restrict__ epf,
                                                   const float* __restrict__ x,
                                                   f16* __restrict__ xf) {
  const int b = blockIdx.x;
  if (b < 8192) {
    const int i = b * 256 + threadIdx.x;  // 2^21 total
    const int e = i & 7;
    const int lane = (i >> 3) & 63;
    const int half = (i >> 9) & 1;
    const int ob = (i >> 10) & 127;
    const int h = i >> 17;
    const int g = lane >> 4, cl = lane & 15;
    const int o = ob * 16 - 1024 + cl;
    const int p = (o <= 0) ? -o : (NP - o);
    const int d = half * 32 + g * 8 + e;
    epf[i] = (f16)er[(size_t)(h * NP + p) * NHD + d];
  } else {
    const int i = (b - 8192) * 256 + threadIdx.x;
    xf[i] = (f16)x[i];
  }
}

// ---------------- kernel 0b: transpose both W matrices f32 -> f16 [N][K] ----------------
// grid.x: [0,48) -> Wqkv (N=3072), [48,64) -> Wo (N=1024). K = 1024 for both.
__global__ __launch_bounds__(256) void trans2_k(const float* __restrict__ Wqkv,
                                                f16* __restrict__ WTqkv,
                                                const float* __restrict__ Wo,
                                                f16* __restrict__ WTo) {
  __shared__ float tile[64][68];
  const int bx = blockIdx.x;
  const float* W;
  f16* WT;
  int N, n0;
  if (bx < 48) { W = Wqkv; WT = WTqkv; N = 3072; n0 = bx * 64; }
  else         { W = Wo;   WT = WTo;   N = 1024; n0 = (bx - 48) * 64; }
  const int k0 = blockIdx.y * 64;
  const int t = threadIdx.x;
  const int rc = t & 15;
  const int rr0 = t >> 4;
#pragma unroll
  for (int i = 0; i < 4; ++i) {
    const int row = rr0 + i * 16;
    float4 v = *(const float4*)(W + (size_t)(k0 + row) * N + n0 + rc * 4);
    *(float4*)&tile[row][rc * 4] = v;
  }
  __syncthreads();
  const int n = t >> 2, kc = (t & 3) * 16;
  f16x8 h0, h1;
#pragma unroll
  for (int e = 0; e < 8; ++e) h0[e] = (f16)tile[kc + e][n];
#pragma unroll
  for (int e = 0; e < 8; ++e) h1[e] = (f16)tile[kc + 8 + e][n];
  f16* dst = WT + (size_t)(n0 + n) * ND + k0 + kc;
  *(f16x8*)dst = h0;
  *(f16x8*)(dst + 8) = h1;
}

// ---------------- kernel 1: QKV projection GEMM (f16, 64x128 tile, BK=64 as 2x32 sub-tiles) ----------------
// Grid: x = n-tile (24, fast), y = m-tile (32). T2 source swizzle per 32-k sub-tile.
__global__ __launch_bounds__(256) void qkv_gemm_k(const f16* __restrict__ Xf,
                                                  const f16* __restrict__ WT,
                                                  const float* __restrict__ bias,
                                                  f16* __restrict__ qf,
                                                  f16* __restrict__ kp, f16* __restrict__ vp) {
  __shared__ f16 sA[2][64 * 32], sB[2][128 * 32];  // 24 KB
  const int t = threadIdx.x;
  const int lane = t & 63;
  const int w = t >> 6;
  const int cl = lane & 15;
  const int g = lane >> 4;
  const int m0 = blockIdx.y * 64;
  const int n0 = blockIdx.x * 128;

  const int arow = w * 16 + (lane >> 2);
  const int brow0 = w * 32 + (lane >> 2);
  const int scol = ((lane & 3) ^ ((lane >> 3) & 3)) * 8;  // T2 source swizzle
  const int rsw = (g ^ ((cl >> 1) & 3)) * 8;              // swizzled read col

  f32x4 acc[4][2] = {};

  for (int k0 = 0; k0 < ND; k0 += 64) {
#pragma unroll
    for (int kc = 0; kc < 2; ++kc) {
      const int kk = k0 + kc * 32;
      gload16(Xf + (size_t)(m0 + arow) * ND + kk + scol, &sA[kc][w * 512]);
      const f16* gb0 = WT + (size_t)(n0 + brow0) * ND + kk + scol;
      gload16(gb0, &sB[kc][w * 1024]);
      gload16(gb0 + (size_t)16 * ND, &sB[kc][w * 1024 + 512]);
    }
    __syncthreads();

#pragma unroll
    for (int kc = 0; kc < 2; ++kc) {
      f16x8 ah[4], bh[2];
#pragma unroll
      for (int fm = 0; fm < 4; ++fm) ah[fm] = *(const f16x8*)&sA[kc][(fm * 16 + cl) * 32 + rsw];
#pragma unroll
      for (int fn = 0; fn < 2; ++fn) bh[fn] = *(const f16x8*)&sB[kc][(w * 32 + fn * 16 + cl) * 32 + rsw];
#pragma unroll
      for (int fm = 0; fm < 4; ++fm)
#pragma unroll
        for (int fn = 0; fn < 2; ++fn)
          acc[fm][fn] = MFMA16x16x32F(ah[fm], bh[fn], acc[fm][fn]);
    }
    __syncthreads();
  }

  // epilogue: bias + scatter into attention layouts (all f16)
#pragma unroll
  for (int fm = 0; fm < 4; ++fm) {
#pragma unroll
    for (int fn = 0; fn < 2; ++fn) {
#pragma unroll
      for (int reg = 0; reg < 4; ++reg) {
        const int gm = m0 + fm * 16 + g * 4 + reg;       // token row
        const int gn = n0 + w * 32 + fn * 16 + cl;       // qkv col
        float val = acc[fm][fn][reg] + bias[gn];
        const int bb = gm >> 10, lpos = gm & 1023;
        const int sec = gn >> 10, hc = gn & 1023;
        const int hh = hc >> 6, dd = hc & 63;
        const int bh = bb * NH + hh;
        if (sec == 0) {
          qf[(size_t)(bh * NL + lpos) * NHD + dd] = (f16)val;
        } else if (sec == 1) {
          // K packed (B-frag): tile jt=lpos>>4, frag f=dd>>5, lane=((dd>>3)&3)*16+(lpos&15), e=dd&7
          const size_t idx = ((size_t)((bh * 64 + (lpos >> 4)) * 2 + (dd >> 5))) * 512 +
                             ((((dd >> 3) & 3) << 4) + (lpos & 15)) * 8 + (dd & 7);
          kp[idx] = (f16)val;
        } else {
          // V packed (B-frag): chunk jc=lpos>>6, t4=dd>>4, half=(lpos>>5)&1,
          // lane=((lpos>>3)&3)*16+(dd&15), e=lpos&7
          const size_t idx = ((size_t)(((bh * 16 + (lpos >> 6)) * 4 + (dd >> 4)) * 2 +
                                       ((lpos >> 5) & 1))) * 512 +
                             ((((lpos >> 3) & 3) << 4) + (dd & 15)) * 8 + (lpos & 7);
          vp[idx] = (f16)val;
        }
      }
    }
  }
}

// ---------------- kernel 2: attention, v10 (all-f16 fragments; unchanged from R12) ----------------
__global__ __launch_bounds__(256) void attn_k(const f16* __restrict__ qf,
                                              const f16* __restrict__ kp, const f16* __restrict__ vp,
                                              const f16* __restrict__ epf,
                                              f16* __restrict__ ao) {
  __shared__ float s_lds[4][16][67];
  __shared__ f16 p_lds[4][16][72];
  __shared__ float mb[4][16], lbuf[4][16], linv[16];

  const int t = threadIdx.x;
  const int w = t >> 6;
  const int lane = t & 63;
  const int cl = lane & 15;
  const int g = lane >> 4;

  const int n = blockIdx.x;
  const int xcd = n & 7, idx = n >> 3;
  const int bh = (xcd << 2) | (idx >> 6);
  const int itile = 63 - (idx & 63);
  const int i0 = itile * 16;
  const int h = bh & (NH - 1);
  const int nchunks = (itile >> 2) + 1;

  const f16* qfb = qf + (size_t)(bh * NL + i0 + cl) * NHD + g * 8;
  const f16x8 q_f0 = *(const f16x8*)qfb;
  const f16x8 q_f1 = *(const f16x8*)(qfb + 32);

  f32x4 acc_o[4] = {};
  float m_s = -3e38f, l_s = 0.0f;

  for (int jc = w; jc < nchunks; jc += 4) {
    const int j0 = jc * 64;
    const int delta = i0 - j0;

    // ---- V fragments (contiguous 1KB streams) ----
    const f16* vbase = vp + ((size_t)(bh * 16 + (j0 >> 6)) * 8) * 512 + lane * 8;
    f16x8 vf[4][2];
#pragma unroll
    for (int t4 = 0; t4 < 4; ++t4) {
      vf[t4][0] = *(const f16x8*)(vbase + (t4 * 2 + 0) * 512);
      vf[t4][1] = *(const f16x8*)(vbase + (t4 * 2 + 1) * 512);
    }

    // ---- S = Q K^T ----
    const f16* kbase = kp + ((size_t)(bh * 64 + (j0 >> 4)) * 2) * 512 + lane * 8;
    f32x4 acc_s[4];
    __builtin_amdgcn_s_setprio(1);
#pragma unroll
    for (int jn = 0; jn < 4; ++jn) {
      f16x8 kf0 = *(const f16x8*)(kbase + (jn * 2 + 0) * 512);
      f16x8 kf1 = *(const f16x8*)(kbase + (jn * 2 + 1) * 512);
      f32x4 a = {};
      a = MFMA16x16x32F(q_f0, kf0, a);
      a = MFMA16x16x32F(q_f1, kf1, a);
      acc_s[jn] = a;
    }

    // ---- bias: 5 Er tiles ----
    const int ob0 = (delta >> 4) + 60;
    const f16* ebase = epf + ((size_t)(h * 128 + ob0) * 2) * 512 + lane * 8;
    f32x4 acc_e[5];
#pragma unroll
    for (int tt = 0; tt < 5; ++tt) {
      f16x8 ef0 = *(const f16x8*)(ebase + (tt * 2 + 0) * 512);
      f16x8 ef1 = *(const f16x8*)(ebase + (tt * 2 + 1) * 512);
      f32x4 c = {};
      c = MFMA16x16x32F(q_f0, ef0, c);
      c = MFMA16x16x32F(q_f1, ef1, c);
      acc_e[tt] = c;
    }
    __builtin_amdgcn_s_setprio(0);

    // ---- in-register diagonal gather of E into S; spill combined to LDS ----
#pragma unroll
    for (int reg = 0; reg < 4; ++reg) {
      const int r = g * 4 + reg;
      const int src = (g << 4) | ((r - cl) & 15);
      const bool ge = (r >= cl);
#pragma unroll
      for (int jn = 0; jn < 4; ++jn) {
        float e_hi = __shfl(acc_e[4 - jn][reg], src);
        float e_lo = __shfl(acc_e[3 - jn][reg], src);
        s_lds[w][r][jn * 16 + cl] = fmaf(acc_s[jn][reg], 0.125f, ge ? e_hi : e_lo);
      }
    }
    wave_sync_lds();

    // ---- online softmax; lane handles row=cl, cols g*16..g*16+15 ----
    float sv[16];
    float tmax = -3e38f;
#pragma unroll
    for (int cc = 0; cc < 16; ++cc) {
      const int c = g * 16 + cc;
      float v = s_lds[w][cl][c];
      if (c > delta + cl) v = -3e38f;
      sv[cc] = v;
      tmax = fmaxf(tmax, v);
    }
    tmax = fmaxf(tmax, __shfl_xor(tmax, 16));
    tmax = fmaxf(tmax, __shfl_xor(tmax, 32));
    const float m_new = fmaxf(m_s, tmax);
    const float fsc = __builtin_amdgcn_exp2f((m_s - m_new) * 1.44269504f);
    float psum = 0.0f;
    f16x8 plo, phi;
#pragma unroll
    for (int cc = 0; cc < 16; ++cc) {
      float pv = __builtin_amdgcn_exp2f((sv[cc] - m_new) * 1.44269504f);
      psum += pv;
      if (cc < 8) plo[cc & 7] = (f16)pv;
      else        phi[cc & 7] = (f16)pv;
    }
    psum += __shfl_xor(psum, 16);
    psum += __shfl_xor(psum, 32);
    l_s = l_s * fsc + psum;
    m_s = m_new;

    *(f16x8*)&p_lds[w][cl][g * 16] = plo;
    *(f16x8*)&p_lds[w][cl][g * 16 + 8] = phi;
    wave_sync_lds();
    f16x8 pf0 = *(const f16x8*)&p_lds[w][cl][g * 8];
    f16x8 pf1 = *(const f16x8*)&p_lds[w][cl][32 + g * 8];

    float fr[4];
#pragma unroll
    for (int reg = 0; reg < 4; ++reg) fr[reg] = __shfl(fsc, g * 4 + reg);
#pragma unroll
    for (int t4 = 0; t4 < 4; ++t4) {
#pragma unroll
      for (int reg = 0; reg < 4; ++reg) acc_o[t4][reg] *= fr[reg];
    }
    __builtin_amdgcn_s_setprio(1);
#pragma unroll
    for (int t4 = 0; t4 < 4; ++t4) {
      acc_o[t4] = MFMA16x16x32F(pf0, vf[t4][0], acc_o[t4]);
      acc_o[t4] = MFMA16x16x32F(pf1, vf[t4][1], acc_o[t4]);
    }
    __builtin_amdgcn_s_setprio(0);
  }

  // ---- flash-merge the 4 waves' partials (s_lds reused as obuf) ----
  if (lane < 16) {
    mb[w][lane] = m_s;
    lbuf[w][lane] = l_s;
  }
  __syncthreads();
  const float M = fmaxf(fmaxf(mb[0][cl], mb[1][cl]), fmaxf(mb[2][cl], mb[3][cl]));
  const float sc = __builtin_amdgcn_exp2f((m_s - M) * 1.44269504f);
  float Lt = 0.0f;
#pragma unroll
  for (int ww = 0; ww < 4; ++ww)
    Lt += lbuf[ww][cl] * __builtin_amdgcn_exp2f((mb[ww][cl] - M) * 1.44269504f);
  if (w == 0 && lane < 16) linv[lane] = 1.0f / Lt;
  float fr2[4];
#pragma unroll
  for (int reg = 0; reg < 4; ++reg) fr2[reg] = __shfl(sc, g * 4 + reg);
#pragma unroll
  for (int t4 = 0; t4 < 4; ++t4) {
#pragma unroll
    for (int reg = 0; reg < 4; ++reg)
      s_lds[w][g * 4 + reg][t4 * 16 + cl] = acc_o[t4][reg] * fr2[reg];
  }
  __syncthreads();
  const int bb = bh >> 4;
#pragma unroll
  for (int rep = 0; rep < 4; ++rep) {
    const int o_ = t + rep * 256;
    const int r = o_ >> 6, c = o_ & 63;
    float s = s_lds[0][r][c] + s_lds[1][r][c] + s_lds[2][r][c] + s_lds[3][r][c];
    ao[(size_t)(bb * NL + i0 + r) * ND + h * NHD + c] = (f16)(s * linv[r]);
  }
}

// ---------------- kernel 3: output projection (f16, 64x128 tile, BK=64, T2 swizzle) ----------------
__global__ __launch_bounds__(256) void out_gemm_k(const f16* __restrict__ A,
                                                  const f16* __restrict__ WT,
                                                  const float* __restrict__ bias,
                                                  float* __restrict__ out) {
  __shared__ f16 sA[2][64 * 32], sB[2][128 * 32];
  const int t = threadIdx.x;
  const int lane = t & 63, w = t >> 6;
  const int cl = lane & 15, g = lane >> 4;
  const int m0 = blockIdx.x * 64;
  const int n0 = blockIdx.y * 128;

  const int arow = w * 16 + (lane >> 2);
  const int brow0 = w * 32 + (lane >> 2);
  const int scol = ((lane & 3) ^ ((lane >> 3) & 3)) * 8;
  const int rsw = (g ^ ((cl >> 1) & 3)) * 8;

  f32x4 acc[4][2] = {};

  for (int k0 = 0; k0 < ND; k0 += 64) {
#pragma unroll
    for (int kc = 0; kc < 2; ++kc) {
      const int kk = k0 + kc * 32;
      gload16(A + (size_t)(m0 + arow) * ND + kk + scol, &sA[kc][w * 512]);
      const f16* gb0 = WT + (size_t)(n0 + brow0) * ND + kk + scol;
      gload16(gb0, &sB[kc][w * 1024]);
      gload16(gb0 + (size_t)16 * ND, &sB[kc][w * 1024 + 512]);
    }
    __syncthreads();
#pragma unroll
    for (int kc = 0; kc < 2; ++kc) {
      f16x8 ah[4], bh[2];
#pragma unroll
      for (int fm = 0; fm < 4; ++fm) ah[fm] = *(const f16x8*)&sA[kc][(fm * 16 + cl) * 32 + rsw];
#pragma unroll
      for (int fn = 0; fn < 2; ++fn) bh[fn] = *(const f16x8*)&sB[kc][(w * 32 + fn * 16 + cl) * 32 + rsw];
#pragma unroll
      for (int fm = 0; fm < 4; ++fm)
#pragma unroll
        for (int fn = 0; fn < 2; ++fn)
          acc[fm][fn] = MFMA16x16x32F(ah[fm], bh[fn], acc[fm][fn]);
    }
    __syncthreads();
  }
#pragma unroll
  for (int fm = 0; fm < 4; ++fm) {
#pragma unroll
    for (int fn = 0; fn < 2; ++fn) {
#pragma unroll
      for (int reg = 0; reg < 4; ++reg) {
        const int gm = m0 + fm * 16 + g * 4 + reg;
        const int gn = n0 + w * 32 + fn * 16 + cl;
        out[(size_t)gm * ND + gn] = acc[fm][fn][reg] + bias[gn];
      }
    }
  }
}

extern "C" void kernel_launch(void* const* d_in, const int* in_sizes, int n_in,
                              void* d_out, int out_size, void* d_ws, size_t ws_size,
                              hipStream_t stream) {
  (void)in_sizes; (void)n_in; (void)out_size; (void)ws_size;
  const float* x = (const float*)d_in[0];
  // d_in[1] = causal mask — structural (triu k=1), computed inline
  const float* Wqkv = (const float*)d_in[2];
  const float* bqkv = (const float*)d_in[3];
  const float* Wo = (const float*)d_in[4];
  const float* bo = (const float*)d_in[5];
  const float* Er = (const float*)d_in[6];

  char* ws = (char*)d_ws;
  size_t off = 0;
  auto take = [&](size_t bytes) {
    char* p = ws + off;
    off += (bytes + 255) & ~(size_t)255;
    return p;
  };
  const size_t qkN = (size_t)NBH * NL * NHD;       // 2,097,152
  const size_t xN = (size_t)NB * NL * ND;          // 2,097,152
  const size_t erpN = (size_t)NH * 128 * 2 * 512;  // 2,097,152
  f16* epf = (f16*)take(erpN * 2);
  f16* qfw = (f16*)take(qkN * 2);
  f16* kpw = (f16*)take(qkN * 2);    // K frag-packed
  f16* vpw = (f16*)take(qkN * 2);    // V frag-packed
  f16* wqkvt = (f16*)take((size_t)3 * ND * ND * 2);  // [3072][1024]
  f16* wot   = (f16*)take((size_t)ND * ND * 2);      // [1024][1024]
  f16* xf    = (f16*)take(xN * 2);                   // X f16
  f16* aow = wqkvt;  // alias: wqkvt dead after qkv_gemm, aow born in attn

  prep_pack_k<<<16384, 256, 0, stream>>>(Er, epf, x, xf);
  trans2_k<<<dim3(64, 16), 256, 0, stream>>>(Wqkv, wqkvt, Wo, wot);
  qkv_gemm_k<<<dim3(24, 32), 256, 0, stream>>>(xf, wqkvt, bqkv, qfw, kpw, vpw);
  attn_k<<<2048, 256, 0, stream>>>(qfw, kpw, vpw, epf, aow);
  out_gemm_k<<<dim3(32, 8), 256, 0, stream>>>(aow, wot, bo, (float*)d_out);
}

// Round 14
// 85.545 us; speedup vs baseline: 1.4668x; 1.0185x over previous
//
#include <hip/hip_runtime.h>

typedef _Float16 f16;
typedef _Float16 f16x8 __attribute__((ext_vector_type(8)));
typedef float f32x4 __attribute__((ext_vector_type(4)));

static_assert(sizeof(f16x8) == 16, "f16x8 must be 16B");

#define MFMA16x16x32F(a, b, c) __builtin_amdgcn_mfma_f32_16x16x32_f16((a), (b), (c), 0, 0, 0)

// problem constants
#define NB 2
#define NL 1024
#define ND 1024
#define NH 16
#define NHD 64
#define NP 2047
#define NBH (NB * NH)  // 32

// wave-synchronous LDS fence (wave-private LDS slices): no vmcnt drain
__device__ __forceinline__ void wave_sync_lds() {
  __builtin_amdgcn_sched_barrier(0);
  asm volatile("s_waitcnt lgkmcnt(0)" ::: "memory");
  __builtin_amdgcn_sched_barrier(0);
}

// async global->LDS, 16B per lane, wave-linear dest
__device__ __forceinline__ void gload16(const f16* g, f16* lds) {
  __builtin_amdgcn_global_load_lds((const __attribute__((address_space(1))) void*)g,
                                   (__attribute__((address_space(3))) void*)lds, 16, 0, 0);
}

// ---------------- kernel 0: fused prep — Er frag-pack + X cast + both W transposes ----------------
// blocks [0,8192): er_pack; [8192,16384): X cast; [16384,17408): W transposes.
__global__ __launch_bounds__(256) void prep_all_k(const float* __restrict__ er,
                                                  f16* __restrict__ epf,
                                                  const float* __restrict__ x,
                                                  f16* __restrict__ xf,
                                                  const float* __restrict__ Wqkv,
                                                  f16* __restrict__ WTqkv,
                                                  const float* __restrict__ Wo,
                                                  f16* __restrict__ WTo) {
  const int b = blockIdx.x;
  const int t = threadIdx.x;
  if (b < 8192) {
    const int i = b * 256 + t;  // 2^21 total
    const int e = i & 7;
    const int lane = (i >> 3) & 63;
    const int half = (i >> 9) & 1;
    const int ob = (i >> 10) & 127;
    const int h = i >> 17;
    const int g = lane >> 4, cl = lane & 15;
    const int o = ob * 16 - 1024 + cl;
    const int p = (o <= 0) ? -o : (NP - o);
    const int d = half * 32 + g * 8 + e;
    epf[i] = (f16)er[(size_t)(h * NP + p) * NHD + d];
  } else if (b < 16384) {
    const int i = (b - 8192) * 256 + t;
    xf[i] = (f16)x[i];
  } else {
    __shared__ float tile[64][68];
    const int b2 = b - 16384;           // [0,1024)
    const int bx = b2 >> 4;             // [0,64)
    const int k0 = (b2 & 15) * 64;
    const float* W;
    f16* WT;
    int N, n0;
    if (bx < 48) { W = Wqkv; WT = WTqkv; N = 3072; n0 = bx * 64; }
    else         { W = Wo;   WT = WTo;   N = 1024; n0 = (bx - 48) * 64; }
    const int rc = t & 15;
    const int rr0 = t >> 4;
#pragma unroll
    for (int i = 0; i < 4; ++i) {
      const int row = rr0 + i * 16;
      float4 v = *(const float4*)(W + (size_t)(k0 + row) * N + n0 + rc * 4);
      *(float4*)&tile[row][rc * 4] = v;
    }
    __syncthreads();
    const int n = t >> 2, kc = (t & 3) * 16;
    f16x8 h0, h1;
#pragma unroll
    for (int e = 0; e < 8; ++e) h0[e] = (f16)tile[kc + e][n];
#pragma unroll
    for (int e = 0; e < 8; ++e) h1[e] = (f16)tile[kc + 8 + e][n];
    f16* dst = WT + (size_t)(n0 + n) * ND + k0 + kc;
    *(f16x8*)dst = h0;
    *(f16x8*)(dst + 8) = h1;
  }
}

// ---------------- kernel 1: QKV projection GEMM (f16, 64x128 tile, BK=64 as 2x32 sub-tiles) ----------------
// Grid: x = n-tile (24, fast), y = m-tile (32). T2 source swizzle per 32-k sub-tile.
__global__ __launch_bounds__(256) void qkv_gemm_k(const f16* __restrict__ Xf,
                                                  const f16* __restrict__ WT,
                                                  const float* __restrict__ bias,
                                                  f16* __restrict__ qf,
                                                  f16* __restrict__ kp, f16* __restrict__ vp) {
  __shared__ f16 sA[2][64 * 32], sB[2][128 * 32];  // 24 KB
  const int t = threadIdx.x;
  const int lane = t & 63;
  const int w = t >> 6;
  const int cl = lane & 15;
  const int g = lane >> 4;
  const int m0 = blockIdx.y * 64;
  const int n0 = blockIdx.x * 128;

  const int arow = w * 16 + (lane >> 2);
  const int brow0 = w * 32 + (lane >> 2);
  const int scol = ((lane & 3) ^ ((lane >> 3) & 3)) * 8;  // T2 source swizzle
  const int rsw = (g ^ ((cl >> 1) & 3)) * 8;              // swizzled read col

  f32x4 acc[4][2] = {};

  for (int k0 = 0; k0 < ND; k0 += 64) {
#pragma unroll
    for (int kc = 0; kc < 2; ++kc) {
      const int kk = k0 + kc * 32;
      gload16(Xf + (size_t)(m0 + arow) * ND + kk + scol, &sA[kc][w * 512]);
      const f16* gb0 = WT + (size_t)(n0 + brow0) * ND + kk + scol;
      gload16(gb0, &sB[kc][w * 1024]);
      gload16(gb0 + (size_t)16 * ND, &sB[kc][w * 1024 + 512]);
    }
    __syncthreads();

#pragma unroll
    for (int kc = 0; kc < 2; ++kc) {
      f16x8 ah[4], bh[2];
#pragma unroll
      for (int fm = 0; fm < 4; ++fm) ah[fm] = *(const f16x8*)&sA[kc][(fm * 16 + cl) * 32 + rsw];
#pragma unroll
      for (int fn = 0; fn < 2; ++fn) bh[fn] = *(const f16x8*)&sB[kc][(w * 32 + fn * 16 + cl) * 32 + rsw];
#pragma unroll
      for (int fm = 0; fm < 4; ++fm)
#pragma unroll
        for (int fn = 0; fn < 2; ++fn)
          acc[fm][fn] = MFMA16x16x32F(ah[fm], bh[fn], acc[fm][fn]);
    }
    __syncthreads();
  }

  // epilogue: bias + scatter into attention layouts (all f16)
#pragma unroll
  for (int fm = 0; fm < 4; ++fm) {
#pragma unroll
    for (int fn = 0; fn < 2; ++fn) {
#pragma unroll
      for (int reg = 0; reg < 4; ++reg) {
        const int gm = m0 + fm * 16 + g * 4 + reg;       // token row
        const int gn = n0 + w * 32 + fn * 16 + cl;       // qkv col
        float val = acc[fm][fn][reg] + bias[gn];
        const int bb = gm >> 10, lpos = gm & 1023;
        const int sec = gn >> 10, hc = gn & 1023;
        const int hh = hc >> 6, dd = hc & 63;
        const int bh = bb * NH + hh;
        if (sec == 0) {
          qf[(size_t)(bh * NL + lpos) * NHD + dd] = (f16)val;
        } else if (sec == 1) {
          // K packed (B-frag): tile jt=lpos>>4, frag f=dd>>5, lane=((dd>>3)&3)*16+(lpos&15), e=dd&7
          const size_t idx = ((size_t)((bh * 64 + (lpos >> 4)) * 2 + (dd >> 5))) * 512 +
                             ((((dd >> 3) & 3) << 4) + (lpos & 15)) * 8 + (dd & 7);
          kp[idx] = (f16)val;
        } else {
          // V packed (B-frag): chunk jc=lpos>>6, t4=dd>>4, half=(lpos>>5)&1,
          // lane=((lpos>>3)&3)*16+(dd&15), e=lpos&7
          const size_t idx = ((size_t)(((bh * 16 + (lpos >> 6)) * 4 + (dd >> 4)) * 2 +
                                       ((lpos >> 5) & 1))) * 512 +
                             ((((lpos >> 3) & 3) << 4) + (dd & 15)) * 8 + (lpos & 7);
          vp[idx] = (f16)val;
        }
      }
    }
  }
}

// ---------------- kernel 2: attention, v11 ----------------
// v10 + A-frag-aligned softmax column assignment: lane (g,cl) handles cols
// {g*8..g*8+7} U {32+g*8..+7} so P lands directly in the PV A-fragment — p_lds
// round-trip and second fence deleted. Values bit-identical to v10.
__global__ __launch_bounds__(256) void attn_k(const f16* __restrict__ qf,
                                              const f16* __restrict__ kp, const f16* __restrict__ vp,
                                              const f16* __restrict__ epf,
                                              f16* __restrict__ ao) {
  __shared__ float s_lds[4][16][67];
  __shared__ float mb[4][16], lbuf[4][16], linv[16];

  const int t = threadIdx.x;
  const int w = t >> 6;
  const int lane = t & 63;
  const int cl = lane & 15;
  const int g = lane >> 4;

  const int n = blockIdx.x;
  const int xcd = n & 7, idx = n >> 3;
  const int bh = (xcd << 2) | (idx >> 6);
  const int itile = 63 - (idx & 63);
  const int i0 = itile * 16;
  const int h = bh & (NH - 1);
  const int nchunks = (itile >> 2) + 1;

  const f16* qfb = qf + (size_t)(bh * NL + i0 + cl) * NHD + g * 8;
  const f16x8 q_f0 = *(const f16x8*)qfb;
  const f16x8 q_f1 = *(const f16x8*)(qfb + 32);

  f32x4 acc_o[4] = {};
  float m_s = -3e38f, l_s = 0.0f;

  for (int jc = w; jc < nchunks; jc += 4) {
    const int j0 = jc * 64;
    const int delta = i0 - j0;

    // ---- V fragments (contiguous 1KB streams) ----
    const f16* vbase = vp + ((size_t)(bh * 16 + (j0 >> 6)) * 8) * 512 + lane * 8;
    f16x8 vf[4][2];
#pragma unroll
    for (int t4 = 0; t4 < 4; ++t4) {
      vf[t4][0] = *(const f16x8*)(vbase + (t4 * 2 + 0) * 512);
      vf[t4][1] = *(const f16x8*)(vbase + (t4 * 2 + 1) * 512);
    }

    // ---- S = Q K^T ----
    const f16* kbase = kp + ((size_t)(bh * 64 + (j0 >> 4)) * 2) * 512 + lane * 8;
    f32x4 acc_s[4];
    __builtin_amdgcn_s_setprio(1);
#pragma unroll
    for (int jn = 0; jn < 4; ++jn) {
      f16x8 kf0 = *(const f16x8*)(kbase + (jn * 2 + 0) * 512);
      f16x8 kf1 = *(const f16x8*)(kbase + (jn * 2 + 1) * 512);
      f32x4 a = {};
      a = MFMA16x16x32F(q_f0, kf0, a);
      a = MFMA16x16x32F(q_f1, kf1, a);
      acc_s[jn] = a;
    }

    // ---- bias: 5 Er tiles ----
    const int ob0 = (delta >> 4) + 60;
    const f16* ebase = epf + ((size_t)(h * 128 + ob0) * 2) * 512 + lane * 8;
    f32x4 acc_e[5];
#pragma unroll
    for (int tt = 0; tt < 5; ++tt) {
      f16x8 ef0 = *(const f16x8*)(ebase + (tt * 2 + 0) * 512);
      f16x8 ef1 = *(const f16x8*)(ebase + (tt * 2 + 1) * 512);
      f32x4 c = {};
      c = MFMA16x16x32F(q_f0, ef0, c);
      c = MFMA16x16x32F(q_f1, ef1, c);
      acc_e[tt] = c;
    }
    __builtin_amdgcn_s_setprio(0);

    // ---- in-register diagonal gather of E into S; spill combined to LDS ----
#pragma unroll
    for (int reg = 0; reg < 4; ++reg) {
      const int r = g * 4 + reg;
      const int src = (g << 4) | ((r - cl) & 15);
      const bool ge = (r >= cl);
#pragma unroll
      for (int jn = 0; jn < 4; ++jn) {
        float e_hi = __shfl(acc_e[4 - jn][reg], src);
        float e_lo = __shfl(acc_e[3 - jn][reg], src);
        s_lds[w][r][jn * 16 + cl] = fmaf(acc_s[jn][reg], 0.125f, ge ? e_hi : e_lo);
      }
    }
    wave_sync_lds();

    // ---- online softmax; lane (g,cl): row=cl, cols {g*8+cc} U {32+g*8+cc} ----
    float sv[16];
    float tmax = -3e38f;
#pragma unroll
    for (int cc = 0; cc < 16; ++cc) {
      const int c = (cc < 8) ? (g * 8 + cc) : (32 + g * 8 + (cc - 8));
      float v = s_lds[w][cl][c];
      if (c > delta + cl) v = -3e38f;
      sv[cc] = v;
      tmax = fmaxf(tmax, v);
    }
    tmax = fmaxf(tmax, __shfl_xor(tmax, 16));
    tmax = fmaxf(tmax, __shfl_xor(tmax, 32));
    const float m_new = fmaxf(m_s, tmax);
    const float fsc = __builtin_amdgcn_exp2f((m_s - m_new) * 1.44269504f);
    float psum = 0.0f;
    f16x8 pf0, pf1;  // P lands directly in A-frag layout — no LDS round-trip
#pragma unroll
    for (int cc = 0; cc < 16; ++cc) {
      float pv = __builtin_amdgcn_exp2f((sv[cc] - m_new) * 1.44269504f);
      psum += pv;
      if (cc < 8) pf0[cc & 7] = (f16)pv;
      else        pf1[cc & 7] = (f16)pv;
    }
    psum += __shfl_xor(psum, 16);
    psum += __shfl_xor(psum, 32);
    l_s = l_s * fsc + psum;
    m_s = m_new;

    // rescale O per row (factors via shfl), accumulate PV
    float fr[4];
#pragma unroll
    for (int reg = 0; reg < 4; ++reg) fr[reg] = __shfl(fsc, g * 4 + reg);
#pragma unroll
    for (int t4 = 0; t4 < 4; ++t4) {
#pragma unroll
      for (int reg = 0; reg < 4; ++reg) acc_o[t4][reg] *= fr[reg];
    }
    __builtin_amdgcn_s_setprio(1);
#pragma unroll
    for (int t4 = 0; t4 < 4; ++t4) {
      acc_o[t4] = MFMA16x16x32F(pf0, vf[t4][0], acc_o[t4]);
      acc_o[t4] = MFMA16x16x32F(pf1, vf[t4][1], acc_o[t4]);
    }
    __builtin_amdgcn_s_setprio(0);
  }

  // ---- flash-merge the 4 waves' partials (s_lds reused as obuf) ----
  if (lane < 16) {
    mb[w][lane] = m_s;
    lbuf[w][lane] = l_s;
  }
  __syncthreads();
  const float M = fmaxf(fmaxf(mb[0][cl], mb[1][cl]), fmaxf(mb[2][cl], mb[3][cl]));
  const float sc = __builtin_amdgcn_exp2f((m_s - M) * 1.44269504f);
  float Lt = 0.0f;
#pragma unroll
  for (int ww = 0; ww < 4; ++ww)
    Lt += lbuf[ww][cl] * __builtin_amdgcn_exp2f((mb[ww][cl] - M) * 1.44269504f);
  if (w == 0 && lane < 16) linv[lane] = 1.0f / Lt;
  float fr2[4];
#pragma unroll
  for (int reg = 0; reg < 4; ++reg) fr2[reg] = __shfl(sc, g * 4 + reg);
#pragma unroll
  for (int t4 = 0; t4 < 4; ++t4) {
#pragma unroll
    for (int reg = 0; reg < 4; ++reg)
      s_lds[w][g * 4 + reg][t4 * 16 + cl] = acc_o[t4][reg] * fr2[reg];
  }
  __syncthreads();
  const int bb = bh >> 4;
#pragma unroll
  for (int rep = 0; rep < 4; ++rep) {
    const int o_ = t + rep * 256;
    const int r = o_ >> 6, c = o_ & 63;
    float s = s_lds[0][r][c] + s_lds[1][r][c] + s_lds[2][r][c] + s_lds[3][r][c];
    ao[(size_t)(bb * NL + i0 + r) * ND + h * NHD + c] = (f16)(s * linv[r]);
  }
}

// ---------------- kernel 3: output projection (f16, 64x128 tile, BK=64, T2 swizzle) ----------------
__global__ __launch_bounds__(256) void out_gemm_k(const f16* __restrict__ A,
                                                  const f16* __restrict__ WT,
                                                  const float* __restrict__ bias,
                                                  float* __restrict__ out) {
  __shared__ f16 sA[2][64 * 32], sB[2][128 * 32];
  const int t = threadIdx.x;
  const int lane = t & 63, w = t >> 6;
  const int cl = lane & 15, g = lane >> 4;
  const int m0 = blockIdx.x * 64;
  const int n0 = blockIdx.y * 128;

  const int arow = w * 16 + (lane >> 2);
  const int brow0 = w * 32 + (lane >> 2);
  const int scol = ((lane & 3) ^ ((lane >> 3) & 3)) * 8;
  const int rsw = (g ^ ((cl >> 1) & 3)) * 8;

  f32x4 acc[4][2] = {};

  for (int k0 = 0; k0 < ND; k0 += 64) {
#pragma unroll
    for (int kc = 0; kc < 2; ++kc) {
      const int kk = k0 + kc * 32;
      gload16(A + (size_t)(m0 + arow) * ND + kk + scol, &sA[kc][w * 512]);
      const f16* gb0 = WT + (size_t)(n0 + brow0) * ND + kk + scol;
      gload16(gb0, &sB[kc][w * 1024]);
      gload16(gb0 + (size_t)16 * ND, &sB[kc][w * 1024 + 512]);
    }
    __syncthreads();
#pragma unroll
    for (int kc = 0; kc < 2; ++kc) {
      f16x8 ah[4], bh[2];
#pragma unroll
      for (int fm = 0; fm < 4; ++fm) ah[fm] = *(const f16x8*)&sA[kc][(fm * 16 + cl) * 32 + rsw];
#pragma unroll
      for (int fn = 0; fn < 2; ++fn) bh[fn] = *(const f16x8*)&sB[kc][(w * 32 + fn * 16 + cl) * 32 + rsw];
#pragma unroll
      for (int fm = 0; fm < 4; ++fm)
#pragma unroll
        for (int fn = 0; fn < 2; ++fn)
          acc[fm][fn] = MFMA16x16x32F(ah[fm], bh[fn], acc[fm][fn]);
    }
    __syncthreads();
  }
#pragma unroll
  for (int fm = 0; fm < 4; ++fm) {
#pragma unroll
    for (int fn = 0; fn < 2; ++fn) {
#pragma unroll
      for (int reg = 0; reg < 4; ++reg) {
        const int gm = m0 + fm * 16 + g * 4 + reg;
        const int gn = n0 + w * 32 + fn * 16 + cl;
        out[(size_t)gm * ND + gn] = acc[fm][fn][reg] + bias[gn];
      }
    }
  }
}

extern "C" void kernel_launch(void* const* d_in, const int* in_sizes, int n_in,
                              void* d_out, int out_size, void* d_ws, size_t ws_size,
                              hipStream_t stream) {
  (void)in_sizes; (void)n_in; (void)out_size; (void)ws_size;
  const float* x = (const float*)d_in[0];
  // d_in[1] = causal mask — structural (triu k=1), computed inline
  const float* Wqkv = (const float*)d_in[2];
  const float* bqkv = (const float*)d_in[3];
  const float* Wo = (const float*)d_in[4];
  const float* bo = (const float*)d_in[5];
  const float* Er = (const float*)d_in[6];

  char* ws = (char*)d_ws;
  size_t off = 0;
  auto take = [&](size_t bytes) {
    char* p = ws + off;
    off += (bytes + 255) & ~(size_t)255;
    return p;
  };
  const size_t qkN = (size_t)NBH * NL * NHD;       // 2,097,152
  const size_t xN = (size_t)NB * NL * ND;          // 2,097,152
  const size_t erpN = (size_t)NH * 128 * 2 * 512;  // 2,097,152
  f16* epf = (f16*)take(erpN * 2);
  f16* qfw = (f16*)take(qkN * 2);
  f16* kpw = (f16*)take(qkN * 2);    // K frag-packed
  f16* vpw = (f16*)take(qkN * 2);    // V frag-packed
  f16* wqkvt = (f16*)take((size_t)3 * ND * ND * 2);  // [3072][1024]
  f16* wot   = (f16*)take((size_t)ND * ND * 2);      // [1024][1024]
  f16* xf    = (f16*)take(xN * 2);                   // X f16
  f16* aow = wqkvt;  // alias: wqkvt dead after qkv_gemm, aow born in attn

  prep_all_k<<<17408, 256, 0, stream>>>(Er, epf, x, xf, Wqkv, wqkvt, Wo, wot);
  qkv_gemm_k<<<dim3(24, 32), 256, 0, stream>>>(xf, wqkvt, bqkv, qfw, kpw, vpw);
  attn_k<<<2048, 256, 0, stream>>>(qfw, kpw, vpw, epf, aow);
  out_gemm_k<<<dim3(32, 8), 256, 0, stream>>>(aow, wot, bo, (float*)d_out);
}